// Round 5
// baseline (115.503 us; speedup 1.0000x reference)
//
#include <hip/hip_runtime.h>

// ---------- types ----------
typedef __bf16 bf16x8 __attribute__((ext_vector_type(8)));
typedef unsigned short u16x8 __attribute__((ext_vector_type(8)));
typedef unsigned short u16x4 __attribute__((ext_vector_type(4)));
typedef float  f32x4  __attribute__((ext_vector_type(4)));

#define QSCALE 0.1803368801111204f   // 0.125 * log2(e): S comes out in log2 domain
#define NHALF 4                       // KV-split factor

__device__ __forceinline__ unsigned short f2bf(float f) {
  unsigned int u = __float_as_uint(f);
  u = u + 0x7fffu + ((u >> 16) & 1u);   // RNE
  return (unsigned short)(u >> 16);
}

// global_load_lds, 16B per lane; LDS dest = wave-uniform base + lane*16
#define GLD16(src, dst)                                                        \
  __builtin_amdgcn_global_load_lds(                                            \
      (const __attribute__((address_space(1))) void*)(src),                    \
      (__attribute__((address_space(3))) void*)(dst), 16, 0, 0)

// All MFMA LDS tiles have 128-byte rows; swizzle: byte ^= (row&7)<<4 (both sides).

// ---------- 1. merged weight transposes ----------
__global__ __launch_bounds__(256) void k_trw(const float* __restrict__ Wq,
                                             const float* __restrict__ Wp,
                                             unsigned short* __restrict__ wqT,
                                             unsigned short* __restrict__ wpT) {
  __shared__ float tile[64][193];
  const int t = threadIdx.x;
  if (blockIdx.x < 32) {
    const int k0 = blockIdx.x * 64;
#pragma unroll
    for (int i = 0; i < 12; ++i) {       // 64 rows x 48 float4
      int u = i * 256 + t;
      int row = u / 48, c4 = u % 48;
      float4 v = *(const float4*)(Wq + (size_t)(k0 + row) * 192 + c4 * 4);
      tile[row][c4 * 4 + 0] = v.x; tile[row][c4 * 4 + 1] = v.y;
      tile[row][c4 * 4 + 2] = v.z; tile[row][c4 * 4 + 3] = v.w;
    }
    __syncthreads();
#pragma unroll
    for (int i = 0; i < 6; ++i) {        // 192 cols x 8 u16x8
      int u = i * 256 + t;
      int c = u >> 3, k8 = (u & 7) * 8;
      u16x8 h;
#pragma unroll
      for (int j = 0; j < 8; ++j) h[j] = f2bf(tile[k8 + j][c]);
      *(u16x8*)(wqT + (size_t)c * 2048 + k0 + k8) = h;
    }
  } else {
    const int n0 = (blockIdx.x - 32) * 64;
#pragma unroll
    for (int i = 0; i < 4; ++i) {        // 64 d-rows x 16 float4
      int u = i * 256 + t;
      int dd = u >> 4, c4 = u & 15;
      float4 v = *(const float4*)(Wp + (size_t)dd * 2048 + n0 + c4 * 4);
      tile[dd][c4 * 4 + 0] = v.x; tile[dd][c4 * 4 + 1] = v.y;
      tile[dd][c4 * 4 + 2] = v.z; tile[dd][c4 * 4 + 3] = v.w;
    }
    __syncthreads();
#pragma unroll
    for (int i = 0; i < 2; ++i) {        // 64 n-rows x 8 u16x8
      int u = i * 256 + t;
      int n = u >> 3, d8 = (u & 7) * 8;
      u16x8 h;
      h[0] = f2bf(tile[d8 + 0][n]); h[1] = f2bf(tile[d8 + 1][n]);
      h[2] = f2bf(tile[d8 + 2][n]); h[3] = f2bf(tile[d8 + 3][n]);
      h[4] = f2bf(tile[d8 + 4][n]); h[5] = f2bf(tile[d8 + 5][n]);
      h[6] = f2bf(tile[d8 + 6][n]); h[7] = f2bf(tile[d8 + 7][n]);
      *(u16x8*)(wpT + (size_t)(n0 + n) * 64 + d8) = h;
    }
  }
}

// ---------- 2. fused QKV GEMM: [16384,2048] x [2048,192] ----------
// BM=32, BN=192, BK=64. 256 threads = 4 waves (1M x 4N), grid 512 = 2 blocks/CU.
__global__ __launch_bounds__(256) void k_qkv(const float* __restrict__ x,
                                             const unsigned short* __restrict__ wqT,
                                             const float* __restrict__ b_qkv,
                                             unsigned short* __restrict__ qb,
                                             unsigned short* __restrict__ kb,
                                             unsigned short* __restrict__ vt) {
  __shared__ __align__(16) char lds[57344];  // sA[d]: d*4096 ; sB[d]: 8192+d*24576
  const int t = threadIdx.x;
  const int lane = t & 63, w = t >> 6;
  const int l15 = lane & 15, l4 = lane >> 4;
  const int m0 = blockIdx.x * 32;

  const int arow = t >> 3;            // 0..31
  const int akc  = (t & 7) * 8;       // 0..56
  const float* xrow = x + (size_t)(m0 + arow) * 2048 + akc;
  const int aoff = arow * 128 + ((akc * 2) ^ ((arow & 7) << 4));

  f32x4 acc[2][3] = {};
  float4 xa0_0, xa1_0, xa0_1, xa1_1;   // 2-deep x prefetch, parity = kt&1

  auto issueA_0 = [&](int kt) {
    xa0_0 = *(const float4*)(xrow + kt * 64);
    xa1_0 = *(const float4*)(xrow + kt * 64 + 4);
  };
  auto issueA_1 = [&](int kt) {
    xa0_1 = *(const float4*)(xrow + kt * 64);
    xa1_1 = *(const float4*)(xrow + kt * 64 + 4);
  };
  auto writeA_0 = [&]() {
    u16x8 h;
    h[0] = f2bf(xa0_0.x); h[1] = f2bf(xa0_0.y); h[2] = f2bf(xa0_0.z); h[3] = f2bf(xa0_0.w);
    h[4] = f2bf(xa1_0.x); h[5] = f2bf(xa1_0.y); h[6] = f2bf(xa1_0.z); h[7] = f2bf(xa1_0.w);
    *(u16x8*)(lds + 0 * 4096 + aoff) = h;
  };
  auto writeA_1 = [&]() {
    u16x8 h;
    h[0] = f2bf(xa0_1.x); h[1] = f2bf(xa0_1.y); h[2] = f2bf(xa0_1.z); h[3] = f2bf(xa0_1.w);
    h[4] = f2bf(xa1_1.x); h[5] = f2bf(xa1_1.y); h[6] = f2bf(xa1_1.z); h[7] = f2bf(xa1_1.w);
    *(u16x8*)(lds + 1 * 4096 + aoff) = h;
  };
  auto stageB = [&](int kt, int d) {
    char* bbase = lds + 8192 + d * 24576;
#pragma unroll
    for (int p = 0; p < 6; ++p) {       // 24KB: 6 x (256 threads x 16B)
      int L = p * 4096 + (w << 10) + (lane << 4);
      int row = L >> 7;
      int cb = (L & 127) ^ ((row & 7) << 4);
      GLD16((const char*)wqT + (size_t)row * 4096 + kt * 128 + cb,
            bbase + p * 4096 + (w << 10));
    }
  };
  auto compute = [&](int d) {
    const char* aB = lds + d * 4096;
    const char* bB = lds + 8192 + d * 24576;
    __builtin_amdgcn_s_setprio(1);
#pragma unroll
    for (int kk = 0; kk < 2; ++kk) {
      int cb = kk * 64 + l4 * 16;
      bf16x8 af[2], bfr[3];
#pragma unroll
      for (int m = 0; m < 2; ++m) {
        int r = m * 16 + l15;
        af[m] = *(const bf16x8*)(aB + r * 128 + (cb ^ ((r & 7) << 4)));
      }
#pragma unroll
      for (int n = 0; n < 3; ++n) {
        int r = w * 48 + n * 16 + l15;
        bfr[n] = *(const bf16x8*)(bB + r * 128 + (cb ^ ((r & 7) << 4)));
      }
#pragma unroll
      for (int m = 0; m < 2; ++m)
#pragma unroll
        for (int n = 0; n < 3; ++n)
          acc[m][n] = __builtin_amdgcn_mfma_f32_16x16x32_bf16(af[m], bfr[n], acc[m][n], 0, 0, 0);
    }
    __builtin_amdgcn_s_setprio(0);
  };

  // FIFO (steady, step n): enter [A(n+1)2, B(n)6]; +A(n+2)2 +B(n+1)6;
  // vmcnt(8) keeps [A(n+2), B(n+1)], drains A(n+1), B(n).
#define QKV_STEP(n, P, DOI, DOS, W)                                    \
  {                                                                    \
    writeA_##P();                                                      \
    if (DOI) issueA_##P((n) + 2);                                      \
    if (DOS) stageB((n) + 1, (P) ^ 1);                                 \
    asm volatile("s_waitcnt vmcnt(" W ") lgkmcnt(0)" ::: "memory");    \
    __builtin_amdgcn_s_barrier();                                      \
    compute(P);                                                        \
    __builtin_amdgcn_s_barrier();                                      \
  }

  issueA_0(0); issueA_1(1); stageB(0, 0);
  for (int kt = 0; kt < 30; kt += 2) {
    QKV_STEP(kt,     0, true, true, "8");
    QKV_STEP(kt + 1, 1, true, true, "8");
  }
  QKV_STEP(30, 0, false, true,  "6");   // drains B(30) (and A(31), older)
  QKV_STEP(31, 1, false, false, "0");
#undef QKV_STEP

  // epilogue: C/D layout col=lane&15, row=(lane>>4)*4+reg
#pragma unroll
  for (int m = 0; m < 2; ++m)
#pragma unroll
    for (int n = 0; n < 3; ++n) {
      int c = w * 48 + n * 16 + l15;    // 0..191
      int j = c >> 6, cc = c & 63;
      float bias = b_qkv[c];
      int grow0 = m0 + m * 16 + l4 * 4;
      if (j == 0) {
#pragma unroll
        for (int r = 0; r < 4; ++r)
          qb[(size_t)(grow0 + r) * 64 + cc] = f2bf((acc[m][n][r] + bias) * QSCALE);
      } else if (j == 1) {
#pragma unroll
        for (int r = 0; r < 4; ++r)
          kb[(size_t)(grow0 + r) * 64 + cc] = f2bf(acc[m][n][r] + bias);
      } else {            // v transposed: [b][64][2048]
        int bbv = grow0 >> 11, nn0 = grow0 & 2047;
        u16x4 h;
        h[0] = f2bf(acc[m][n][0] + bias); h[1] = f2bf(acc[m][n][1] + bias);
        h[2] = f2bf(acc[m][n][2] + bias); h[3] = f2bf(acc[m][n][3] + bias);
        *(u16x4*)(vt + ((size_t)bbv * 64 + cc) * 2048 + nn0) = h;
      }
    }
}

// ---------- 3. flash attention, swapped-operand (S^T), KV-split x4 ----------
// grid (32 qtile, 8 batch, 4 kv-quarter) = 1024 blocks = 4/CU. 4 waves x 16 q-rows.
__global__ __launch_bounds__(256) void k_attn(const unsigned short* __restrict__ qb,
                                              const unsigned short* __restrict__ kb,
                                              const unsigned short* __restrict__ vt,
                                              float* __restrict__ ctxp,
                                              float* __restrict__ mlp) {
  __shared__ __align__(16) char lds[32768];  // sK[d]: d*8192 ; sV[d]: 16384+d*8192
  const int t = threadIdx.x;
  const int lane = t & 63, w = t >> 6;
  const int l15 = lane & 15, l4 = lane >> 4;
  const int bb = blockIdx.y;
  const int half = blockIdx.z;
  const int q0 = blockIdx.x * 64 + w * 16;
  const int kt0 = half * 8;
  const unsigned short* qrow = qb + ((size_t)bb * 2048 + q0 + l15) * 64;
  bf16x8 aq[2];
  aq[0] = *(const bf16x8*)(qrow + l4 * 8);       // B-frag: col=l15(q), k=(l>>4)*8+j
  aq[1] = *(const bf16x8*)(qrow + 32 + l4 * 8);
  f32x4 ctx[4] = {};                              // ctx^T: q=l15, d=df*16+l4*4+r
  float m = -1e30f, lsum = 0.f;
  const char* kBase = (const char*)kb + (size_t)bb * 2048 * 128;
  const char* vBase = (const char*)vt + (size_t)bb * 64 * 4096;
  const int srcA = ((l4 & 1) << 5) | l15;
  const int srcB = srcA + 16;
  const bool hi = (l4 >> 1) & 1;

  auto stage = [&](int kt, int d) {
#pragma unroll
    for (int p = 0; p < 2; ++p) {
      int L = p * 4096 + (w << 10) + (lane << 4);
      int row = L >> 7;
      int cb = (L & 127) ^ ((row & 7) << 4);
      GLD16(kBase + (size_t)(kt * 64 + row) * 128 + cb,
            lds + d * 8192 + p * 4096 + (w << 10));
      GLD16(vBase + (size_t)row * 4096 + kt * 128 + cb,
            lds + 16384 + d * 8192 + p * 4096 + (w << 10));
    }
  };

  stage(kt0, 0);
  int d = 0;
  for (int kt = 0; kt < 8; ++kt) {
    if (kt < 7) {
      stage(kt0 + kt + 1, d ^ 1);
      asm volatile("s_waitcnt vmcnt(4)" ::: "memory");   // drains tile kt, keeps prefetch
    } else {
      asm volatile("s_waitcnt vmcnt(0)" ::: "memory");
    }
    __builtin_amdgcn_s_barrier();
    const char* sK = lds + d * 8192;
    const char* sV = lds + 16384 + d * 8192;
    // S^T = K Q^T : s[mf] holds q=l15, kv = mf*16 + l4*4 + r  (log2 domain)
    f32x4 s[4] = {};
    __builtin_amdgcn_s_setprio(1);
#pragma unroll
    for (int kk = 0; kk < 2; ++kk) {
      int cb = kk * 64 + l4 * 16;
#pragma unroll
      for (int mf = 0; mf < 4; ++mf) {
        int r = mf * 16 + l15;
        bf16x8 kf = *(const bf16x8*)(sK + r * 128 + (cb ^ ((r & 7) << 4)));
        s[mf] = __builtin_amdgcn_mfma_f32_16x16x32_bf16(kf, aq[kk], s[mf], 0, 0, 0);
      }
    }
    __builtin_amdgcn_s_setprio(0);
    float pm = fmaxf(fmaxf(fmaxf(s[0][0], s[0][1]), fmaxf(s[0][2], s[0][3])),
                     fmaxf(fmaxf(s[1][0], s[1][1]), fmaxf(s[1][2], s[1][3])));
    pm = fmaxf(pm, fmaxf(fmaxf(fmaxf(s[2][0], s[2][1]), fmaxf(s[2][2], s[2][3])),
                         fmaxf(fmaxf(s[3][0], s[3][1]), fmaxf(s[3][2], s[3][3]))));
    pm = fmaxf(pm, __shfl_xor(pm, 16));
    pm = fmaxf(pm, __shfl_xor(pm, 32));
    if (!__all(pm <= m + 11.5f)) {     // T13 defer-max (log2 domain)
      float mn = fmaxf(m, pm);
      float al = __builtin_exp2f(m - mn);
      m = mn; lsum *= al;
#pragma unroll
      for (int df = 0; df < 4; ++df)
#pragma unroll
        for (int r = 0; r < 4; ++r) ctx[df][r] *= al;
    }
    float lp = 0.f;
#pragma unroll
    for (int mf = 0; mf < 4; ++mf)
#pragma unroll
      for (int r = 0; r < 4; ++r) {
        float p = __builtin_exp2f(s[mf][r] - m);
        s[mf][r] = p;
        lp += p;
      }
    lsum += lp;
    unsigned int pk[4][2];
#pragma unroll
    for (int mf = 0; mf < 4; ++mf) {
      asm("v_cvt_pk_bf16_f32 %0, %1, %2" : "=v"(pk[mf][0]) : "v"(s[mf][0]), "v"(s[mf][1]));
      asm("v_cvt_pk_bf16_f32 %0, %1, %2" : "=v"(pk[mf][1]) : "v"(s[mf][2]), "v"(s[mf][3]));
    }
    // ctx^T += V^T P^T
#pragma unroll
    for (int kk = 0; kk < 2; ++kk) {
      unsigned int q00 = __shfl((int)pk[2 * kk][0], srcA);
      unsigned int q10 = __shfl((int)pk[2 * kk + 1][0], srcA);
      unsigned int q01 = __shfl((int)pk[2 * kk][1], srcA);
      unsigned int q11 = __shfl((int)pk[2 * kk + 1][1], srcA);
      unsigned int r00 = __shfl((int)pk[2 * kk][0], srcB);
      unsigned int r10 = __shfl((int)pk[2 * kk + 1][0], srcB);
      unsigned int r01 = __shfl((int)pk[2 * kk][1], srcB);
      unsigned int r11 = __shfl((int)pk[2 * kk + 1][1], srcB);
      uint4 uu;
      uu.x = hi ? q10 : q00;
      uu.y = hi ? q11 : q01;
      uu.z = hi ? r10 : r00;
      uu.w = hi ? r11 : r01;
      bf16x8 pfrag = *(bf16x8*)&uu;
      int cb = kk * 64 + l4 * 16;
      __builtin_amdgcn_s_setprio(1);
#pragma unroll
      for (int df = 0; df < 4; ++df) {
        int rv = df * 16 + l15;
        bf16x8 vf = *(const bf16x8*)(sV + rv * 128 + (cb ^ ((rv & 7) << 4)));
        ctx[df] = __builtin_amdgcn_mfma_f32_16x16x32_bf16(vf, pfrag, ctx[df], 0, 0, 0);
      }
      __builtin_amdgcn_s_setprio(0);
    }
    __builtin_amdgcn_s_barrier();
    d ^= 1;
  }
  lsum += __shfl_xor(lsum, 16);
  lsum += __shfl_xor(lsum, 32);
  size_t g = (size_t)bb * 2048 + q0 + l15;
#pragma unroll
  for (int df = 0; df < 4; ++df) {
    f32x4 c = ctx[df];
    *(float4*)(ctxp + ((size_t)half * 16384 + g) * 64 + df * 16 + l4 * 4) =
        *(float4*)&c;
  }
  if (l4 == 0) {
    float2 ml = make_float2(m, lsum);
    *(float2*)(mlp + ((size_t)half * 16384 + g) * 2) = ml;
  }
}

// ---------- 4. proj GEMM, combine-once, n-chunk loop ----------
// grid 512 (BM=32), 256 thr = 4 waves. 8 chunks of 256 cols, dbuf wpT staging.
__global__ __launch_bounds__(256) void k_proj(const float* __restrict__ ctxp,
                                              const float* __restrict__ mlp,
                                              const unsigned short* __restrict__ wpT,
                                              const float* __restrict__ b_proj,
                                              float* __restrict__ out) {
  __shared__ __align__(16) char lds[69632];   // sA: 0..4KB ; sB[d]: 4096+d*32768
  const int t = threadIdx.x;
  const int lane = t & 63, w = t >> 6;
  const int l15 = lane & 15, l4 = lane >> 4;
  const int m0 = blockIdx.x * 32;

  // preload all bias for this block's 8 chunks (keeps vmcnt FIFO clean in-loop)
  float4 bias_r[8];
#pragma unroll
  for (int c = 0; c < 8; ++c)
    bias_r[c] = *(const float4*)(b_proj + c * 256 + w * 64 + l4 * 4);
  // note: bias col for frag n adds n*16 -> handled at store via separate loads?
  // No: we need per-n bias; preload [8][4] instead:
  float4 bias_n[8][4];
#pragma unroll
  for (int c = 0; c < 8; ++c)
#pragma unroll
    for (int n = 0; n < 4; ++n)
      bias_n[c][n] = *(const float4*)(b_proj + c * 256 + w * 64 + n * 16 + l4 * 4);

  // stage sA: combine NHALF halves -> bf16 [32][64], swizzled
  {
    int r_ = t >> 3;                     // 0..31
    int d8 = (t & 7) * 8;                // 8 d-values
    size_t g = (size_t)m0 + r_;
    float mh[NHALF], lh[NHALF];
#pragma unroll
    for (int h = 0; h < NHALF; ++h) {
      float2 ml = *(const float2*)(mlp + ((size_t)h * 16384 + g) * 2);
      mh[h] = ml.x; lh[h] = ml.y;
    }
    float M = fmaxf(fmaxf(mh[0], mh[1]), fmaxf(mh[2], mh[3]));
    float ah[NHALF];
    float den = 0.f;
#pragma unroll
    for (int h = 0; h < NHALF; ++h) {
      ah[h] = __builtin_exp2f(mh[h] - M);
      den += lh[h] * ah[h];
    }
    float inv = 1.0f / den;
#pragma unroll
    for (int h = 0; h < NHALF; ++h) ah[h] *= inv;
    float accd[8] = {};
#pragma unroll
    for (int h = 0; h < NHALF; ++h) {
      const float4* p = (const float4*)(ctxp + ((size_t)h * 16384 + g) * 64 + d8);
      float4 v0 = p[0], v1 = p[1];
      accd[0] += v0.x * ah[h]; accd[1] += v0.y * ah[h];
      accd[2] += v0.z * ah[h]; accd[3] += v0.w * ah[h];
      accd[4] += v1.x * ah[h]; accd[5] += v1.y * ah[h];
      accd[6] += v1.z * ah[h]; accd[7] += v1.w * ah[h];
    }
    u16x8 o;
#pragma unroll
    for (int j = 0; j < 8; ++j) o[j] = f2bf(accd[j]);
    *(u16x8*)(lds + r_ * 128 + ((d8 * 2) ^ ((r_ & 7) << 4))) = o;
  }

  auto stageB = [&](int c, int d) {      // wpT rows c*256..+255 (128B each) -> 32KB
    char* bbase = lds + 4096 + d * 32768;
#pragma unroll
    for (int p = 0; p < 8; ++p) {
      int L = p * 4096 + (w << 10) + (lane << 4);
      int row = L >> 7;
      int cb = (L & 127) ^ ((row & 7) << 4);
      GLD16((const char*)wpT + (size_t)(c * 256 + row) * 128 + cb,
            bbase + p * 4096 + (w << 10));
    }
  };

  stageB(0, 0); stageB(1, 1);
#pragma unroll
  for (int c = 0; c < 8; ++c) {
    // FIFO: [stage(c), st(c-1), stage(c+1)] -> vmcnt(8) keeps stage(c+1)
    asm volatile("s_waitcnt vmcnt(8) lgkmcnt(0)" ::: "memory");
    __builtin_amdgcn_s_barrier();
    const char* bB = lds + 4096 + (c & 1) * 32768;
    f32x4 acc[2][4] = {};
    __builtin_amdgcn_s_setprio(1);
#pragma unroll
    for (int kk = 0; kk < 2; ++kk) {
      int cb = kk * 64 + l4 * 16;
      bf16x8 af[2], bfr[4];
#pragma unroll
      for (int m = 0; m < 2; ++m) {
        int r = m * 16 + l15;
        af[m] = *(const bf16x8*)(lds + r * 128 + (cb ^ ((r & 7) << 4)));
      }
#pragma unroll
      for (int n = 0; n < 4; ++n) {
        int r = w * 64 + n * 16 + l15;
        bfr[n] = *(const bf16x8*)(bB + r * 128 + (cb ^ ((r & 7) << 4)));
      }
      // swapped: A=wpT-rows (out cols), B=ctx-rows (out rows)
#pragma unroll
      for (int m = 0; m < 2; ++m)
#pragma unroll
        for (int n = 0; n < 4; ++n)
          acc[m][n] = __builtin_amdgcn_mfma_f32_16x16x32_bf16(bfr[n], af[m], acc[m][n], 0, 0, 0);
    }
    __builtin_amdgcn_s_setprio(0);
#pragma unroll
    for (int m = 0; m < 2; ++m)
#pragma unroll
      for (int n = 0; n < 4; ++n) {
        int grow = m0 + m * 16 + l15;
        int gcol = c * 256 + w * 64 + n * 16 + l4 * 4;
        float4 bias = bias_n[c][n];
        float4 o;
        o.x = acc[m][n][0] + bias.x; o.y = acc[m][n][1] + bias.y;
        o.z = acc[m][n][2] + bias.z; o.w = acc[m][n][3] + bias.w;
        *(float4*)(out + (size_t)grow * 2048 + gcol) = o;
      }
    __builtin_amdgcn_s_barrier();        // all reads of buf (c&1) done
    asm volatile("" ::: "memory");       // pin store-before-stage issue order
    if (c < 6) stageB(c + 2, c & 1);
  }
}

// ---------- launch ----------
extern "C" void kernel_launch(void* const* d_in, const int* in_sizes, int n_in,
                              void* d_out, int out_size, void* d_ws, size_t ws_size,
                              hipStream_t stream) {
  const float* x      = (const float*)d_in[0];
  const float* W_qkv  = (const float*)d_in[1];
  const float* b_qkv  = (const float*)d_in[2];
  const float* W_proj = (const float*)d_in[3];
  const float* b_proj = (const float*)d_in[4];
  float* out = (float*)d_out;

  unsigned short* ws   = (unsigned short*)d_ws;
  unsigned short* wqT  = ws;                                   // 192*2048
  unsigned short* wpT  = wqT + (size_t)192 * 2048;             // 2048*64
  unsigned short* qb   = wpT + (size_t)2048 * 64;              // 16384*64 (pre-scaled)
  unsigned short* kb   = qb  + (size_t)16384 * 64;
  unsigned short* vt   = kb  + (size_t)16384 * 64;             // [8][64][2048]
  float* ctxp = (float*)(vt + (size_t)16384 * 64);             // [4][16384][64] fp32
  float* mlp  = ctxp + (size_t)NHALF * 16384 * 64;             // [4][16384][2]

  k_trw<<<64, 256, 0, stream>>>(W_qkv, W_proj, wqT, wpT);
  k_qkv<<<512, 256, 0, stream>>>(x, wqT, b_qkv, qb, kb, vt);
  k_attn<<<dim3(32, 8, NHALF), 256, 0, stream>>>(qb, kb, vt, ctxp, mlp);
  k_proj<<<512, 256, 0, stream>>>(ctxp, mlp, wpT, b_proj, out);
}

// Round 6
// 105.590 us; speedup vs baseline: 1.0939x; 1.0939x over previous
//
#include <hip/hip_runtime.h>

// ---------- types ----------
typedef __bf16 bf16x8 __attribute__((ext_vector_type(8)));
typedef unsigned short u16x8 __attribute__((ext_vector_type(8)));
typedef unsigned short u16x4 __attribute__((ext_vector_type(4)));
typedef float  f32x4  __attribute__((ext_vector_type(4)));

#define QSCALE 0.1803368801111204f   // 0.125 * log2(e): S comes out in log2 domain
#define NHALF 2                       // KV-split factor

__device__ __forceinline__ unsigned short f2bf(float f) {
  unsigned int u = __float_as_uint(f);
  u = u + 0x7fffu + ((u >> 16) & 1u);   // RNE
  return (unsigned short)(u >> 16);
}

// global_load_lds, 16B per lane; LDS dest = wave-uniform base + lane*16
#define GLD16(src, dst)                                                        \
  __builtin_amdgcn_global_load_lds(                                            \
      (const __attribute__((address_space(1))) void*)(src),                    \
      (__attribute__((address_space(3))) void*)(dst), 16, 0, 0)

// All MFMA LDS tiles have 128-byte rows; swizzle: byte ^= (row&7)<<4 (both sides).

// ---------- 1. merged weight transposes ----------
__global__ __launch_bounds__(256) void k_trw(const float* __restrict__ Wq,
                                             const float* __restrict__ Wp,
                                             unsigned short* __restrict__ wqT,
                                             unsigned short* __restrict__ wpT) {
  __shared__ float tile[64][193];
  const int t = threadIdx.x;
  if (blockIdx.x < 32) {
    const int k0 = blockIdx.x * 64;
#pragma unroll
    for (int i = 0; i < 12; ++i) {       // 64 rows x 48 float4
      int u = i * 256 + t;
      int row = u / 48, c4 = u % 48;
      float4 v = *(const float4*)(Wq + (size_t)(k0 + row) * 192 + c4 * 4);
      tile[row][c4 * 4 + 0] = v.x; tile[row][c4 * 4 + 1] = v.y;
      tile[row][c4 * 4 + 2] = v.z; tile[row][c4 * 4 + 3] = v.w;
    }
    __syncthreads();
#pragma unroll
    for (int i = 0; i < 6; ++i) {        // 192 cols x 8 u16x8
      int u = i * 256 + t;
      int c = u >> 3, k8 = (u & 7) * 8;
      u16x8 h;
#pragma unroll
      for (int j = 0; j < 8; ++j) h[j] = f2bf(tile[k8 + j][c]);
      *(u16x8*)(wqT + (size_t)c * 2048 + k0 + k8) = h;
    }
  } else {
    const int n0 = (blockIdx.x - 32) * 64;
#pragma unroll
    for (int i = 0; i < 4; ++i) {        // 64 d-rows x 16 float4
      int u = i * 256 + t;
      int dd = u >> 4, c4 = u & 15;
      float4 v = *(const float4*)(Wp + (size_t)dd * 2048 + n0 + c4 * 4);
      tile[dd][c4 * 4 + 0] = v.x; tile[dd][c4 * 4 + 1] = v.y;
      tile[dd][c4 * 4 + 2] = v.z; tile[dd][c4 * 4 + 3] = v.w;
    }
    __syncthreads();
#pragma unroll
    for (int i = 0; i < 2; ++i) {        // 64 n-rows x 8 u16x8
      int u = i * 256 + t;
      int n = u >> 3, d8 = (u & 7) * 8;
      u16x8 h;
      h[0] = f2bf(tile[d8 + 0][n]); h[1] = f2bf(tile[d8 + 1][n]);
      h[2] = f2bf(tile[d8 + 2][n]); h[3] = f2bf(tile[d8 + 3][n]);
      h[4] = f2bf(tile[d8 + 4][n]); h[5] = f2bf(tile[d8 + 5][n]);
      h[6] = f2bf(tile[d8 + 6][n]); h[7] = f2bf(tile[d8 + 7][n]);
      *(u16x8*)(wpT + (size_t)(n0 + n) * 64 + d8) = h;
    }
  }
}

// ---------- 2. fused QKV GEMM: [16384,2048] x [2048,192]  (round-4 verbatim) ----------
// BM=64, BN=192 (q|k|v), BK=64. 512 threads = 8 waves (2M x 4N), grid 256.
__global__ __launch_bounds__(512) void k_qkv(const float* __restrict__ x,
                                             const unsigned short* __restrict__ wqT,
                                             const float* __restrict__ b_qkv,
                                             unsigned short* __restrict__ qb,
                                             unsigned short* __restrict__ kb,
                                             unsigned short* __restrict__ vt) {
  __shared__ __align__(16) char lds[65536];  // sA[d]: d*8192 ; sB[d]: 16384+d*24576
  const int t = threadIdx.x;
  const int lane = t & 63, w = t >> 6;
  const int l15 = lane & 15, l4 = lane >> 4;
  const int wm = w >> 2, wn = w & 3;
  const int m0 = blockIdx.x * 64;

  const int arow = t >> 3;            // 0..63
  const int akc  = (t & 7) * 8;       // 0..56
  const float* xrow = x + (size_t)(m0 + arow) * 2048 + akc;
  const int aoff = arow * 128 + ((akc * 2) ^ ((arow & 7) << 4));

  f32x4 acc[2][3] = {};
  float4 xa0_0, xa1_0, xa0_1, xa1_1;   // 2-deep x prefetch, parity = kt&1

  auto issueA_0 = [&](int kt) {
    xa0_0 = *(const float4*)(xrow + kt * 64);
    xa1_0 = *(const float4*)(xrow + kt * 64 + 4);
  };
  auto issueA_1 = [&](int kt) {
    xa0_1 = *(const float4*)(xrow + kt * 64);
    xa1_1 = *(const float4*)(xrow + kt * 64 + 4);
  };
  auto writeA_0 = [&]() {
    u16x8 h;
    h[0] = f2bf(xa0_0.x); h[1] = f2bf(xa0_0.y); h[2] = f2bf(xa0_0.z); h[3] = f2bf(xa0_0.w);
    h[4] = f2bf(xa1_0.x); h[5] = f2bf(xa1_0.y); h[6] = f2bf(xa1_0.z); h[7] = f2bf(xa1_0.w);
    *(u16x8*)(lds + 0 * 8192 + aoff) = h;
  };
  auto writeA_1 = [&]() {
    u16x8 h;
    h[0] = f2bf(xa0_1.x); h[1] = f2bf(xa0_1.y); h[2] = f2bf(xa0_1.z); h[3] = f2bf(xa0_1.w);
    h[4] = f2bf(xa1_1.x); h[5] = f2bf(xa1_1.y); h[6] = f2bf(xa1_1.z); h[7] = f2bf(xa1_1.w);
    *(u16x8*)(lds + 1 * 8192 + aoff) = h;
  };
  auto stageB = [&](int kt, int d) {
    char* bbase = lds + 16384 + d * 24576;
#pragma unroll
    for (int p = 0; p < 3; ++p) {
      int L = p * 8192 + (w << 10) + (lane << 4);
      int row = L >> 7;
      int cb = (L & 127) ^ ((row & 7) << 4);
      GLD16((const char*)wqT + (size_t)row * 4096 + kt * 128 + cb,
            bbase + p * 8192 + (w << 10));
    }
  };
  auto compute = [&](int d) {
    const char* aB = lds + d * 8192;
    const char* bB = lds + 16384 + d * 24576;
    __builtin_amdgcn_s_setprio(1);
#pragma unroll
    for (int kk = 0; kk < 2; ++kk) {
      int cb = kk * 64 + l4 * 16;
      bf16x8 af[2], bfr[3];
#pragma unroll
      for (int m = 0; m < 2; ++m) {
        int r = wm * 32 + m * 16 + l15;
        af[m] = *(const bf16x8*)(aB + r * 128 + (cb ^ ((r & 7) << 4)));
      }
#pragma unroll
      for (int n = 0; n < 3; ++n) {
        int r = wn * 48 + n * 16 + l15;
        bfr[n] = *(const bf16x8*)(bB + r * 128 + (cb ^ ((r & 7) << 4)));
      }
#pragma unroll
      for (int m = 0; m < 2; ++m)
#pragma unroll
        for (int n = 0; n < 3; ++n)
          acc[m][n] = __builtin_amdgcn_mfma_f32_16x16x32_bf16(af[m], bfr[n], acc[m][n], 0, 0, 0);
    }
    __builtin_amdgcn_s_setprio(0);
  };

#define QKV_STEP(n, P, DOI, DOS, W)                                    \
  {                                                                    \
    writeA_##P();                                                      \
    if (DOI) issueA_##P((n) + 2);                                      \
    if (DOS) stageB((n) + 1, (P) ^ 1);                                 \
    asm volatile("s_waitcnt vmcnt(" W ") lgkmcnt(0)" ::: "memory");    \
    __builtin_amdgcn_s_barrier();                                      \
    compute(P);                                                        \
    __builtin_amdgcn_s_barrier();                                      \
  }

  issueA_0(0); issueA_1(1); stageB(0, 0);
  for (int kt = 0; kt < 30; kt += 2) {
    QKV_STEP(kt,     0, true, true, "5");
    QKV_STEP(kt + 1, 1, true, true, "5");
  }
  QKV_STEP(30, 0, false, true,  "5");
  QKV_STEP(31, 1, false, false, "0");
#undef QKV_STEP

  // epilogue: C/D layout col=lane&15, row=(lane>>4)*4+reg
#pragma unroll
  for (int m = 0; m < 2; ++m)
#pragma unroll
    for (int n = 0; n < 3; ++n) {
      int c = wn * 48 + n * 16 + l15;   // 0..191
      int j = c >> 6, cc = c & 63;
      float bias = b_qkv[c];
      int grow0 = m0 + wm * 32 + m * 16 + l4 * 4;
      if (j == 0) {
#pragma unroll
        for (int r = 0; r < 4; ++r)
          qb[(size_t)(grow0 + r) * 64 + cc] = f2bf((acc[m][n][r] + bias) * QSCALE);
      } else if (j == 1) {
#pragma unroll
        for (int r = 0; r < 4; ++r)
          kb[(size_t)(grow0 + r) * 64 + cc] = f2bf(acc[m][n][r] + bias);
      } else {            // v transposed: [b][64][2048]
        int bbv = grow0 >> 11, nn0 = grow0 & 2047;
        u16x4 h;
        h[0] = f2bf(acc[m][n][0] + bias); h[1] = f2bf(acc[m][n][1] + bias);
        h[2] = f2bf(acc[m][n][2] + bias); h[3] = f2bf(acc[m][n][3] + bias);
        *(u16x4*)(vt + ((size_t)bbv * 64 + cc) * 2048 + nn0) = h;
      }
    }
}

// ---------- 3. flash attention, swapped-operand (S^T), KV-split x2 (round-4 verbatim) ----------
__global__ __launch_bounds__(256) void k_attn(const unsigned short* __restrict__ qb,
                                              const unsigned short* __restrict__ kb,
                                              const unsigned short* __restrict__ vt,
                                              float* __restrict__ ctxp,
                                              float* __restrict__ mlp) {
  __shared__ __align__(16) char lds[32768];  // sK[d]: d*8192 ; sV[d]: 16384+d*8192
  const int t = threadIdx.x;
  const int lane = t & 63, w = t >> 6;
  const int l15 = lane & 15, l4 = lane >> 4;
  const int bb = blockIdx.y;
  const int half = blockIdx.z;
  const int q0 = blockIdx.x * 64 + w * 16;
  const int kt0 = half * 16;
  const unsigned short* qrow = qb + ((size_t)bb * 2048 + q0 + l15) * 64;
  bf16x8 aq[2];
  aq[0] = *(const bf16x8*)(qrow + l4 * 8);       // B-frag: col=l15(q), k=(l>>4)*8+j
  aq[1] = *(const bf16x8*)(qrow + 32 + l4 * 8);
  f32x4 ctx[4] = {};                              // ctx^T: q=l15, d=df*16+l4*4+r
  float m = -1e30f, lsum = 0.f;
  const char* kBase = (const char*)kb + (size_t)bb * 2048 * 128;
  const char* vBase = (const char*)vt + (size_t)bb * 64 * 4096;
  const int srcA = ((l4 & 1) << 5) | l15;
  const int srcB = srcA + 16;
  const bool hi = (l4 >> 1) & 1;

  auto stage = [&](int kt, int d) {
#pragma unroll
    for (int p = 0; p < 2; ++p) {
      int L = p * 4096 + (w << 10) + (lane << 4);
      int row = L >> 7;
      int cb = (L & 127) ^ ((row & 7) << 4);
      GLD16(kBase + (size_t)(kt * 64 + row) * 128 + cb,
            lds + d * 8192 + p * 4096 + (w << 10));
      GLD16(vBase + (size_t)row * 4096 + kt * 128 + cb,
            lds + 16384 + d * 8192 + p * 4096 + (w << 10));
    }
  };

  stage(kt0, 0);
  int d = 0;
  for (int kt = 0; kt < 16; ++kt) {
    if (kt < 15) {
      stage(kt0 + kt + 1, d ^ 1);
      asm volatile("s_waitcnt vmcnt(4)" ::: "memory");   // drains tile kt, keeps prefetch
    } else {
      asm volatile("s_waitcnt vmcnt(0)" ::: "memory");
    }
    __builtin_amdgcn_s_barrier();
    const char* sK = lds + d * 8192;
    const char* sV = lds + 16384 + d * 8192;
    // S^T = K Q^T : s[mf] holds q=l15, kv = mf*16 + l4*4 + r  (log2 domain)
    f32x4 s[4] = {};
    __builtin_amdgcn_s_setprio(1);
#pragma unroll
    for (int kk = 0; kk < 2; ++kk) {
      int cb = kk * 64 + l4 * 16;
#pragma unroll
      for (int mf = 0; mf < 4; ++mf) {
        int r = mf * 16 + l15;
        bf16x8 kf = *(const bf16x8*)(sK + r * 128 + (cb ^ ((r & 7) << 4)));
        s[mf] = __builtin_amdgcn_mfma_f32_16x16x32_bf16(kf, aq[kk], s[mf], 0, 0, 0);
      }
    }
    __builtin_amdgcn_s_setprio(0);
    float pm = fmaxf(fmaxf(fmaxf(s[0][0], s[0][1]), fmaxf(s[0][2], s[0][3])),
                     fmaxf(fmaxf(s[1][0], s[1][1]), fmaxf(s[1][2], s[1][3])));
    pm = fmaxf(pm, fmaxf(fmaxf(fmaxf(s[2][0], s[2][1]), fmaxf(s[2][2], s[2][3])),
                         fmaxf(fmaxf(s[3][0], s[3][1]), fmaxf(s[3][2], s[3][3]))));
    pm = fmaxf(pm, __shfl_xor(pm, 16));
    pm = fmaxf(pm, __shfl_xor(pm, 32));
    if (!__all(pm <= m + 11.5f)) {     // T13 defer-max (log2 domain)
      float mn = fmaxf(m, pm);
      float al = __builtin_exp2f(m - mn);
      m = mn; lsum *= al;
#pragma unroll
      for (int df = 0; df < 4; ++df)
#pragma unroll
        for (int r = 0; r < 4; ++r) ctx[df][r] *= al;
    }
    float lp = 0.f;
#pragma unroll
    for (int mf = 0; mf < 4; ++mf)
#pragma unroll
      for (int r = 0; r < 4; ++r) {
        float p = __builtin_exp2f(s[mf][r] - m);
        s[mf][r] = p;
        lp += p;
      }
    lsum += lp;
    unsigned int pk[4][2];
#pragma unroll
    for (int mf = 0; mf < 4; ++mf) {
      asm("v_cvt_pk_bf16_f32 %0, %1, %2" : "=v"(pk[mf][0]) : "v"(s[mf][0]), "v"(s[mf][1]));
      asm("v_cvt_pk_bf16_f32 %0, %1, %2" : "=v"(pk[mf][1]) : "v"(s[mf][2]), "v"(s[mf][3]));
    }
    // ctx^T += V^T P^T
#pragma unroll
    for (int kk = 0; kk < 2; ++kk) {
      unsigned int q00 = __shfl((int)pk[2 * kk][0], srcA);
      unsigned int q10 = __shfl((int)pk[2 * kk + 1][0], srcA);
      unsigned int q01 = __shfl((int)pk[2 * kk][1], srcA);
      unsigned int q11 = __shfl((int)pk[2 * kk + 1][1], srcA);
      unsigned int r00 = __shfl((int)pk[2 * kk][0], srcB);
      unsigned int r10 = __shfl((int)pk[2 * kk + 1][0], srcB);
      unsigned int r01 = __shfl((int)pk[2 * kk][1], srcB);
      unsigned int r11 = __shfl((int)pk[2 * kk + 1][1], srcB);
      uint4 uu;
      uu.x = hi ? q10 : q00;
      uu.y = hi ? q11 : q01;
      uu.z = hi ? r10 : r00;
      uu.w = hi ? r11 : r01;
      bf16x8 pfrag = *(bf16x8*)&uu;
      int cb = kk * 64 + l4 * 16;
      __builtin_amdgcn_s_setprio(1);
#pragma unroll
      for (int df = 0; df < 4; ++df) {
        int rv = df * 16 + l15;
        bf16x8 vf = *(const bf16x8*)(sV + rv * 128 + (cb ^ ((rv & 7) << 4)));
        ctx[df] = __builtin_amdgcn_mfma_f32_16x16x32_bf16(vf, pfrag, ctx[df], 0, 0, 0);
      }
      __builtin_amdgcn_s_setprio(0);
    }
    __builtin_amdgcn_s_barrier();
    d ^= 1;
  }
  lsum += __shfl_xor(lsum, 16);
  lsum += __shfl_xor(lsum, 32);
  size_t g = (size_t)bb * 2048 + q0 + l15;
#pragma unroll
  for (int df = 0; df < 4; ++df) {
    f32x4 c = ctx[df];
    *(float4*)(ctxp + ((size_t)half * 16384 + g) * 64 + df * 16 + l4 * 4) =
        *(float4*)&c;
  }
  if (l4 == 0) {
    float2 ml = make_float2(m, lsum);
    *(float2*)(mlp + ((size_t)half * 16384 + g) * 2) = ml;
  }
}

// ---------- 4. proj GEMM: combine-once, n-chunk loop, dbuf wpT ----------
// grid 256 (BM=64), 512 threads = 8 waves. 8 chunks of 256 cols.
__global__ __launch_bounds__(512) void k_proj(const float* __restrict__ ctxp,
                                              const float* __restrict__ mlp,
                                              const unsigned short* __restrict__ wpT,
                                              const float* __restrict__ b_proj,
                                              float* __restrict__ out) {
  __shared__ __align__(16) char lds[81920]; // sA[0,8K); bias[8K,16K); sB[d]: 16384+d*32768
  const int t = threadIdx.x;
  const int lane = t & 63, w = t >> 6;
  const int l15 = lane & 15, l4 = lane >> 4;
  const int m0 = blockIdx.x * 64;

  // bias -> LDS (one GLD pass: 512 x 16B = 8KB, linear)
  GLD16((const char*)b_proj + (size_t)(w << 10) + (lane << 4), lds + 8192 + (w << 10));

  // combine the 2 KV halves once -> sA bf16 [64][64], swizzled
  {
    int r_ = t >> 3;                     // 0..63
    int d8 = (t & 7) * 8;                // 8 d-values
    size_t g = (size_t)m0 + r_;
    float2 ml0 = *(const float2*)(mlp + g * 2);
    float2 ml1 = *(const float2*)(mlp + ((size_t)16384 + g) * 2);
    float M = fmaxf(ml0.x, ml1.x);
    float a0 = __builtin_exp2f(ml0.x - M), a1 = __builtin_exp2f(ml1.x - M);
    float inv = 1.0f / (ml0.y * a0 + ml1.y * a1);
    a0 *= inv; a1 *= inv;
    const float4* p0 = (const float4*)(ctxp + g * 64 + d8);
    const float4* p1 = (const float4*)(ctxp + ((size_t)16384 + g) * 64 + d8);
    float4 v0a = p0[0], v0b = p0[1], v1a = p1[0], v1b = p1[1];
    u16x8 o;
    o[0] = f2bf(v0a.x * a0 + v1a.x * a1); o[1] = f2bf(v0a.y * a0 + v1a.y * a1);
    o[2] = f2bf(v0a.z * a0 + v1a.z * a1); o[3] = f2bf(v0a.w * a0 + v1a.w * a1);
    o[4] = f2bf(v0b.x * a0 + v1b.x * a1); o[5] = f2bf(v0b.y * a0 + v1b.y * a1);
    o[6] = f2bf(v0b.z * a0 + v1b.z * a1); o[7] = f2bf(v0b.w * a0 + v1b.w * a1);
    *(u16x8*)(lds + r_ * 128 + ((d8 * 2) ^ ((r_ & 7) << 4))) = o;
  }

  auto stageB = [&](int c, int d) {      // wpT rows [c*256, +256), 128B each -> 32KB
    char* bbase = lds + 16384 + d * 32768;
#pragma unroll
    for (int p = 0; p < 4; ++p) {        // 4 x (512 threads x 16B)
      int L = p * 8192 + t * 16;
      int row = L >> 7;
      int cb = (L & 127) ^ ((row & 7) << 4);
      GLD16((const char*)wpT + (size_t)(c * 256 + row) * 128 + cb,
            bbase + p * 8192 + (w << 10));
    }
  };

  stageB(0, 0); stageB(1, 1);
  // vmcnt FIFO (stores count on GFX9): c=0: [st0(4),st1(4)] -> vmcnt(4).
  // steady c: [stores(c-2)(8), stage(c)(4), stores(c-1)(8), stage(c+1)(4)] -> vmcnt(12).
  // c=7: [stores5(8), stage7(4), stores6(8)] -> vmcnt(8).
#pragma unroll
  for (int c = 0; c < 8; ++c) {
    if (c == 0)      asm volatile("s_waitcnt vmcnt(4) lgkmcnt(0)" ::: "memory");
    else if (c == 7) asm volatile("s_waitcnt vmcnt(8) lgkmcnt(0)" ::: "memory");
    else             asm volatile("s_waitcnt vmcnt(12) lgkmcnt(0)" ::: "memory");
    __builtin_amdgcn_s_barrier();
    const char* bB = lds + 16384 + (c & 1) * 32768;
    f32x4 acc[4][2] = {};
    __builtin_amdgcn_s_setprio(1);
#pragma unroll
    for (int kk = 0; kk < 2; ++kk) {
      int cb = kk * 64 + l4 * 16;
      bf16x8 af[4], bfr[2];
#pragma unroll
      for (int m = 0; m < 4; ++m) {
        int r = m * 16 + l15;
        af[m] = *(const bf16x8*)(lds + r * 128 + (cb ^ ((r & 7) << 4)));
      }
#pragma unroll
      for (int n = 0; n < 2; ++n) {
        int r = w * 32 + n * 16 + l15;
        bfr[n] = *(const bf16x8*)(bB + r * 128 + (cb ^ ((r & 7) << 4)));
      }
      // swapped: A=wpT-rows (out cols), B=ctx-rows (out rows)
#pragma unroll
      for (int m = 0; m < 4; ++m)
#pragma unroll
        for (int n = 0; n < 2; ++n)
          acc[m][n] = __builtin_amdgcn_mfma_f32_16x16x32_bf16(bfr[n], af[m], acc[m][n], 0, 0, 0);
    }
    __builtin_amdgcn_s_setprio(0);
#pragma unroll
    for (int m = 0; m < 4; ++m)
#pragma unroll
      for (int n = 0; n < 2; ++n) {
        int grow = m0 + m * 16 + l15;
        int gcol = c * 256 + w * 32 + n * 16 + l4 * 4;
        float4 bias = *(const float4*)(lds + 8192 + gcol * 4);  // lgkm, FIFO-safe
        float4 o;
        o.x = acc[m][n][0] + bias.x; o.y = acc[m][n][1] + bias.y;
        o.z = acc[m][n][2] + bias.z; o.w = acc[m][n][3] + bias.w;
        *(float4*)(out + (size_t)grow * 2048 + gcol) = o;
      }
    __builtin_amdgcn_s_barrier();        // all reads of buf (c&1) done
    if (c < 6) stageB(c + 2, c & 1);
  }
}

// ---------- launch ----------
extern "C" void kernel_launch(void* const* d_in, const int* in_sizes, int n_in,
                              void* d_out, int out_size, void* d_ws, size_t ws_size,
                              hipStream_t stream) {
  const float* x      = (const float*)d_in[0];
  const float* W_qkv  = (const float*)d_in[1];
  const float* b_qkv  = (const float*)d_in[2];
  const float* W_proj = (const float*)d_in[3];
  const float* b_proj = (const float*)d_in[4];
  float* out = (float*)d_out;

  unsigned short* ws   = (unsigned short*)d_ws;
  unsigned short* wqT  = ws;                                   // 192*2048
  unsigned short* wpT  = wqT + (size_t)192 * 2048;             // 2048*64
  unsigned short* qb   = wpT + (size_t)2048 * 64;              // 16384*64 (pre-scaled)
  unsigned short* kb   = qb  + (size_t)16384 * 64;
  unsigned short* vt   = kb  + (size_t)16384 * 64;             // [8][64][2048]
  float* ctxp = (float*)(vt + (size_t)16384 * 64);             // [2][16384][64] fp32
  float* mlp  = ctxp + (size_t)NHALF * 16384 * 64;             // [2][16384][2]

  k_trw<<<64, 256, 0, stream>>>(W_qkv, W_proj, wqT, wpT);
  k_qkv<<<256, 512, 0, stream>>>(x, wqT, b_qkv, qb, kb, vt);
  k_attn<<<dim3(32, 8, NHALF), 256, 0, stream>>>(qb, kb, vt, ctxp, mlp);
  k_proj<<<256, 512, 0, stream>>>(ctxp, mlp, wpT, b_proj, out);
}

// Round 7
// 97.176 us; speedup vs baseline: 1.1886x; 1.0866x over previous
//
#include <hip/hip_runtime.h>

// ---------- types ----------
typedef __bf16 bf16x8 __attribute__((ext_vector_type(8)));
typedef unsigned short u16x8 __attribute__((ext_vector_type(8)));
typedef unsigned short u16x4 __attribute__((ext_vector_type(4)));
typedef float  f32x4  __attribute__((ext_vector_type(4)));

#define QSCALE 0.1803368801111204f   // 0.125 * log2(e): S comes out in log2 domain

__device__ __forceinline__ unsigned short f2bf(float f) {
  unsigned int u = __float_as_uint(f);
  u = u + 0x7fffu + ((u >> 16) & 1u);   // RNE
  return (unsigned short)(u >> 16);
}

// global_load_lds, 16B per lane; LDS dest = wave-uniform base + lane*16
#define GLD16(src, dst)                                                        \
  __builtin_amdgcn_global_load_lds(                                            \
      (const __attribute__((address_space(1))) void*)(src),                    \
      (__attribute__((address_space(3))) void*)(dst), 16, 0, 0)

// All MFMA LDS tiles have 128-byte rows; swizzle: byte ^= (row&7)<<4 (both sides).

// ---------- 1. merged weight transposes (R4 verbatim) ----------
__global__ __launch_bounds__(256) void k_trw(const float* __restrict__ Wq,
                                             const float* __restrict__ Wp,
                                             unsigned short* __restrict__ wqT,
                                             unsigned short* __restrict__ wpT) {
  __shared__ float tile[64][193];
  const int t = threadIdx.x;
  if (blockIdx.x < 32) {
    const int k0 = blockIdx.x * 64;
#pragma unroll
    for (int i = 0; i < 12; ++i) {       // 64 rows x 48 float4
      int u = i * 256 + t;
      int row = u / 48, c4 = u % 48;
      float4 v = *(const float4*)(Wq + (size_t)(k0 + row) * 192 + c4 * 4);
      tile[row][c4 * 4 + 0] = v.x; tile[row][c4 * 4 + 1] = v.y;
      tile[row][c4 * 4 + 2] = v.z; tile[row][c4 * 4 + 3] = v.w;
    }
    __syncthreads();
#pragma unroll
    for (int i = 0; i < 6; ++i) {        // 192 cols x 8 u16x8
      int u = i * 256 + t;
      int c = u >> 3, k8 = (u & 7) * 8;
      u16x8 h;
#pragma unroll
      for (int j = 0; j < 8; ++j) h[j] = f2bf(tile[k8 + j][c]);
      *(u16x8*)(wqT + (size_t)c * 2048 + k0 + k8) = h;
    }
  } else {
    const int n0 = (blockIdx.x - 32) * 64;
#pragma unroll
    for (int i = 0; i < 4; ++i) {        // 64 d-rows x 16 float4
      int u = i * 256 + t;
      int dd = u >> 4, c4 = u & 15;
      float4 v = *(const float4*)(Wp + (size_t)dd * 2048 + n0 + c4 * 4);
      tile[dd][c4 * 4 + 0] = v.x; tile[dd][c4 * 4 + 1] = v.y;
      tile[dd][c4 * 4 + 2] = v.z; tile[dd][c4 * 4 + 3] = v.w;
    }
    __syncthreads();
#pragma unroll
    for (int i = 0; i < 2; ++i) {        // 64 n-rows x 8 u16x8
      int u = i * 256 + t;
      int n = u >> 3, d8 = (u & 7) * 8;
      u16x8 h;
      h[0] = f2bf(tile[d8 + 0][n]); h[1] = f2bf(tile[d8 + 1][n]);
      h[2] = f2bf(tile[d8 + 2][n]); h[3] = f2bf(tile[d8 + 3][n]);
      h[4] = f2bf(tile[d8 + 4][n]); h[5] = f2bf(tile[d8 + 5][n]);
      h[6] = f2bf(tile[d8 + 6][n]); h[7] = f2bf(tile[d8 + 7][n]);
      *(u16x8*)(wpT + (size_t)(n0 + n) * 64 + d8) = h;
    }
  }
}

// ---------- 2. fused QKV GEMM: [16384,2048] x [2048,192]  (R4 verbatim) ----------
__global__ __launch_bounds__(512) void k_qkv(const float* __restrict__ x,
                                             const unsigned short* __restrict__ wqT,
                                             const float* __restrict__ b_qkv,
                                             unsigned short* __restrict__ qb,
                                             unsigned short* __restrict__ kb,
                                             unsigned short* __restrict__ vt) {
  __shared__ __align__(16) char lds[65536];  // sA[d]: d*8192 ; sB[d]: 16384+d*24576
  const int t = threadIdx.x;
  const int lane = t & 63, w = t >> 6;
  const int l15 = lane & 15, l4 = lane >> 4;
  const int wm = w >> 2, wn = w & 3;
  const int m0 = blockIdx.x * 64;

  const int arow = t >> 3;            // 0..63
  const int akc  = (t & 7) * 8;       // 0..56
  const float* xrow = x + (size_t)(m0 + arow) * 2048 + akc;
  const int aoff = arow * 128 + ((akc * 2) ^ ((arow & 7) << 4));

  f32x4 acc[2][3] = {};
  float4 xa0_0, xa1_0, xa0_1, xa1_1;   // 2-deep x prefetch, parity = kt&1

  auto issueA_0 = [&](int kt) {
    xa0_0 = *(const float4*)(xrow + kt * 64);
    xa1_0 = *(const float4*)(xrow + kt * 64 + 4);
  };
  auto issueA_1 = [&](int kt) {
    xa0_1 = *(const float4*)(xrow + kt * 64);
    xa1_1 = *(const float4*)(xrow + kt * 64 + 4);
  };
  auto writeA_0 = [&]() {
    u16x8 h;
    h[0] = f2bf(xa0_0.x); h[1] = f2bf(xa0_0.y); h[2] = f2bf(xa0_0.z); h[3] = f2bf(xa0_0.w);
    h[4] = f2bf(xa1_0.x); h[5] = f2bf(xa1_0.y); h[6] = f2bf(xa1_0.z); h[7] = f2bf(xa1_0.w);
    *(u16x8*)(lds + 0 * 8192 + aoff) = h;
  };
  auto writeA_1 = [&]() {
    u16x8 h;
    h[0] = f2bf(xa0_1.x); h[1] = f2bf(xa0_1.y); h[2] = f2bf(xa0_1.z); h[3] = f2bf(xa0_1.w);
    h[4] = f2bf(xa1_1.x); h[5] = f2bf(xa1_1.y); h[6] = f2bf(xa1_1.z); h[7] = f2bf(xa1_1.w);
    *(u16x8*)(lds + 1 * 8192 + aoff) = h;
  };
  auto stageB = [&](int kt, int d) {
    char* bbase = lds + 16384 + d * 24576;
#pragma unroll
    for (int p = 0; p < 3; ++p) {
      int L = p * 8192 + (w << 10) + (lane << 4);
      int row = L >> 7;
      int cb = (L & 127) ^ ((row & 7) << 4);
      GLD16((const char*)wqT + (size_t)row * 4096 + kt * 128 + cb,
            bbase + p * 8192 + (w << 10));
    }
  };
  auto compute = [&](int d) {
    const char* aB = lds + d * 8192;
    const char* bB = lds + 16384 + d * 24576;
    __builtin_amdgcn_s_setprio(1);
#pragma unroll
    for (int kk = 0; kk < 2; ++kk) {
      int cb = kk * 64 + l4 * 16;
      bf16x8 af[2], bfr[3];
#pragma unroll
      for (int m = 0; m < 2; ++m) {
        int r = wm * 32 + m * 16 + l15;
        af[m] = *(const bf16x8*)(aB + r * 128 + (cb ^ ((r & 7) << 4)));
      }
#pragma unroll
      for (int n = 0; n < 3; ++n) {
        int r = wn * 48 + n * 16 + l15;
        bfr[n] = *(const bf16x8*)(bB + r * 128 + (cb ^ ((r & 7) << 4)));
      }
#pragma unroll
      for (int m = 0; m < 2; ++m)
#pragma unroll
        for (int n = 0; n < 3; ++n)
          acc[m][n] = __builtin_amdgcn_mfma_f32_16x16x32_bf16(af[m], bfr[n], acc[m][n], 0, 0, 0);
    }
    __builtin_amdgcn_s_setprio(0);
  };

#define QKV_STEP(n, P, DOI, DOS, W)                                    \
  {                                                                    \
    writeA_##P();                                                      \
    if (DOI) issueA_##P((n) + 2);                                      \
    if (DOS) stageB((n) + 1, (P) ^ 1);                                 \
    asm volatile("s_waitcnt vmcnt(" W ") lgkmcnt(0)" ::: "memory");    \
    __builtin_amdgcn_s_barrier();                                      \
    compute(P);                                                        \
    __builtin_amdgcn_s_barrier();                                      \
  }

  issueA_0(0); issueA_1(1); stageB(0, 0);
  for (int kt = 0; kt < 30; kt += 2) {
    QKV_STEP(kt,     0, true, true, "5");
    QKV_STEP(kt + 1, 1, true, true, "5");
  }
  QKV_STEP(30, 0, false, true,  "5");
  QKV_STEP(31, 1, false, false, "0");
#undef QKV_STEP

  // epilogue: C/D layout col=lane&15, row=(lane>>4)*4+reg
#pragma unroll
  for (int m = 0; m < 2; ++m)
#pragma unroll
    for (int n = 0; n < 3; ++n) {
      int c = wn * 48 + n * 16 + l15;   // 0..191
      int j = c >> 6, cc = c & 63;
      float bias = b_qkv[c];
      int grow0 = m0 + wm * 32 + m * 16 + l4 * 4;
      if (j == 0) {
#pragma unroll
        for (int r = 0; r < 4; ++r)
          qb[(size_t)(grow0 + r) * 64 + cc] = f2bf((acc[m][n][r] + bias) * QSCALE);
      } else if (j == 1) {
#pragma unroll
        for (int r = 0; r < 4; ++r)
          kb[(size_t)(grow0 + r) * 64 + cc] = f2bf(acc[m][n][r] + bias);
      } else {            // v transposed: [b][64][2048]
        int bbv = grow0 >> 11, nn0 = grow0 & 2047;
        u16x4 h;
        h[0] = f2bf(acc[m][n][0] + bias); h[1] = f2bf(acc[m][n][1] + bias);
        h[2] = f2bf(acc[m][n][2] + bias); h[3] = f2bf(acc[m][n][3] + bias);
        *(u16x4*)(vt + ((size_t)bbv * 64 + cc) * 2048 + nn0) = h;
      }
    }
}

// ---------- 3. fused attention + proj ----------
// grid (32 qtile, 8 batch), 512 threads = 8 waves.
// Phase 1: waves 0-3 attend KV tiles 0-15, waves 4-7 tiles 16-31 (same 64 q-rows).
// Phase 2: LDS combine of the two halves -> bf16 sA [64][64].
// Phase 3: proj chunk loop (8 x 256 cols), dbuf wpT, counted vmcnt.
#define P_CTX1 0          // [0, 16K): half1 ctx exchange (reuses K/V region)
#define P_ML1  16384      // [16K, 16K+512)
#define P_SA   24576      // [24K, 32K)
#define P_BIAS 32768      // [32K, 40K)
#define P_WPT  40960      // [40K, 104K): wpT dbuf 2 x 32K
__global__ __launch_bounds__(512) void k_attnproj(const unsigned short* __restrict__ qb,
                                                  const unsigned short* __restrict__ kb,
                                                  const unsigned short* __restrict__ vt,
                                                  const unsigned short* __restrict__ wpT,
                                                  const float* __restrict__ b_proj,
                                                  float* __restrict__ out) {
  __shared__ __align__(16) char lds[106496];
  const int t = threadIdx.x;
  const int lane = t & 63, w = t >> 6;
  const int l15 = lane & 15, l4 = lane >> 4;
  const int wq = w & 3, wh = w >> 2;
  const int bb = blockIdx.y;
  const int qbase = blockIdx.x * 64;
  const int q0 = qbase + wq * 16;
  const int kt0 = wh * 16;
  const unsigned short* qrow = qb + ((size_t)bb * 2048 + q0 + l15) * 64;
  bf16x8 aq[2];
  aq[0] = *(const bf16x8*)(qrow + l4 * 8);       // B-frag: col=l15(q), k=(l>>4)*8+j
  aq[1] = *(const bf16x8*)(qrow + 32 + l4 * 8);
  f32x4 ctx[4] = {};                              // ctx^T: q=l15, d=df*16+l4*4+r
  float m = -1e30f, lsum = 0.f;
  const char* kBase = (const char*)kb + (size_t)bb * 2048 * 128;
  const char* vBase = (const char*)vt + (size_t)bb * 64 * 4096;
  const int srcA = ((l4 & 1) << 5) | l15;
  const int srcB = srcA + 16;
  const bool hi = (l4 >> 1) & 1;

  // per-half K/V pipeline: half wh at lds + wh*32768; staged by its 4 waves
  auto stage = [&](int kt, int d) {
#pragma unroll
    for (int p = 0; p < 2; ++p) {
      int L = p * 4096 + (wq << 10) + (lane << 4);
      int row = L >> 7;
      int cb = (L & 127) ^ ((row & 7) << 4);
      GLD16(kBase + (size_t)(kt * 64 + row) * 128 + cb,
            lds + wh * 32768 + d * 8192 + p * 4096 + (wq << 10));
      GLD16(vBase + (size_t)row * 4096 + kt * 128 + cb,
            lds + wh * 32768 + 16384 + d * 8192 + p * 4096 + (wq << 10));
    }
  };

  // ---- phase 1 ----
  stage(kt0, 0);
  int d = 0;
  for (int kt = 0; kt < 16; ++kt) {
    if (kt < 15) {
      stage(kt0 + kt + 1, d ^ 1);
      asm volatile("s_waitcnt vmcnt(4)" ::: "memory");   // drains tile kt, keeps prefetch
    } else {
      asm volatile("s_waitcnt vmcnt(0)" ::: "memory");
    }
    __builtin_amdgcn_s_barrier();
    const char* sK = lds + wh * 32768 + d * 8192;
    const char* sV = lds + wh * 32768 + 16384 + d * 8192;
    // S^T = K Q^T : s[mf] holds q=l15, kv = mf*16 + l4*4 + r  (log2 domain)
    f32x4 s[4] = {};
    __builtin_amdgcn_s_setprio(1);
#pragma unroll
    for (int kk = 0; kk < 2; ++kk) {
      int cb = kk * 64 + l4 * 16;
#pragma unroll
      for (int mf = 0; mf < 4; ++mf) {
        int r = mf * 16 + l15;
        bf16x8 kf = *(const bf16x8*)(sK + r * 128 + (cb ^ ((r & 7) << 4)));
        s[mf] = __builtin_amdgcn_mfma_f32_16x16x32_bf16(kf, aq[kk], s[mf], 0, 0, 0);
      }
    }
    __builtin_amdgcn_s_setprio(0);
    float pm = fmaxf(fmaxf(fmaxf(s[0][0], s[0][1]), fmaxf(s[0][2], s[0][3])),
                     fmaxf(fmaxf(s[1][0], s[1][1]), fmaxf(s[1][2], s[1][3])));
    pm = fmaxf(pm, fmaxf(fmaxf(fmaxf(s[2][0], s[2][1]), fmaxf(s[2][2], s[2][3])),
                         fmaxf(fmaxf(s[3][0], s[3][1]), fmaxf(s[3][2], s[3][3]))));
    pm = fmaxf(pm, __shfl_xor(pm, 16));
    pm = fmaxf(pm, __shfl_xor(pm, 32));
    if (!__all(pm <= m + 11.5f)) {     // T13 defer-max (log2 domain)
      float mn = fmaxf(m, pm);
      float al = __builtin_exp2f(m - mn);
      m = mn; lsum *= al;
#pragma unroll
      for (int df = 0; df < 4; ++df)
#pragma unroll
        for (int r = 0; r < 4; ++r) ctx[df][r] *= al;
    }
    float lp = 0.f;
#pragma unroll
    for (int mf = 0; mf < 4; ++mf)
#pragma unroll
      for (int r = 0; r < 4; ++r) {
        float p = __builtin_exp2f(s[mf][r] - m);
        s[mf][r] = p;
        lp += p;
      }
    lsum += lp;
    unsigned int pk[4][2];
#pragma unroll
    for (int mf = 0; mf < 4; ++mf) {
      asm("v_cvt_pk_bf16_f32 %0, %1, %2" : "=v"(pk[mf][0]) : "v"(s[mf][0]), "v"(s[mf][1]));
      asm("v_cvt_pk_bf16_f32 %0, %1, %2" : "=v"(pk[mf][1]) : "v"(s[mf][2]), "v"(s[mf][3]));
    }
    // ctx^T += V^T P^T
#pragma unroll
    for (int kk = 0; kk < 2; ++kk) {
      unsigned int q00 = __shfl((int)pk[2 * kk][0], srcA);
      unsigned int q10 = __shfl((int)pk[2 * kk + 1][0], srcA);
      unsigned int q01 = __shfl((int)pk[2 * kk][1], srcA);
      unsigned int q11 = __shfl((int)pk[2 * kk + 1][1], srcA);
      unsigned int r00 = __shfl((int)pk[2 * kk][0], srcB);
      unsigned int r10 = __shfl((int)pk[2 * kk + 1][0], srcB);
      unsigned int r01 = __shfl((int)pk[2 * kk][1], srcB);
      unsigned int r11 = __shfl((int)pk[2 * kk + 1][1], srcB);
      uint4 uu;
      uu.x = hi ? q10 : q00;
      uu.y = hi ? q11 : q01;
      uu.z = hi ? r10 : r00;
      uu.w = hi ? r11 : r01;
      bf16x8 pfrag = *(bf16x8*)&uu;
      int cb = kk * 64 + l4 * 16;
      __builtin_amdgcn_s_setprio(1);
#pragma unroll
      for (int df = 0; df < 4; ++df) {
        int rv = df * 16 + l15;
        bf16x8 vf = *(const bf16x8*)(sV + rv * 128 + (cb ^ ((rv & 7) << 4)));
        ctx[df] = __builtin_amdgcn_mfma_f32_16x16x32_bf16(vf, pfrag, ctx[df], 0, 0, 0);
      }
      __builtin_amdgcn_s_setprio(0);
    }
    __builtin_amdgcn_s_barrier();
    d ^= 1;
  }
  lsum += __shfl_xor(lsum, 16);
  lsum += __shfl_xor(lsum, 32);

  // ---- phase 2: prefetch proj operands, then LDS combine ----
  auto stageB = [&](int c, int dd) {      // wpT rows [c*256, +256) -> 32KB
    char* bbase = lds + P_WPT + dd * 32768;
#pragma unroll
    for (int p = 0; p < 4; ++p) {         // 4 x (512 threads x 16B)
      int L = p * 8192 + t * 16;
      int row = L >> 7;
      int cb = (L & 127) ^ ((row & 7) << 4);
      GLD16((const char*)wpT + (size_t)(c * 256 + row) * 128 + cb,
            bbase + p * 8192 + (w << 10));
    }
  };
  GLD16((const char*)b_proj + (w << 10) + (lane << 4), lds + P_BIAS + (w << 10));
  stageB(0, 0); stageB(1, 1);

  if (wh == 1) {                         // deposit half1 state
    char* cbase = lds + P_CTX1 + (wq << 12);
#pragma unroll
    for (int df = 0; df < 4; ++df) {
      int byte = l15 * 256 + df * 64 + l4 * 16;
      *(f32x4*)(cbase + (byte ^ ((l15 & 7) << 4))) = ctx[df];
    }
    if (l4 == 0)
      *(float2*)(lds + P_ML1 + wq * 128 + l15 * 8) = make_float2(m, lsum);
  }
  asm volatile("s_waitcnt lgkmcnt(0)" ::: "memory");
  __builtin_amdgcn_sched_barrier(0);
  __builtin_amdgcn_s_barrier();
  if (wh == 0) {                         // merge halves -> sA bf16 [64][64] swizzled
    char* cbase = lds + P_CTX1 + (wq << 12);
    float2 ml1 = *(const float2*)(lds + P_ML1 + wq * 128 + l15 * 8);
    float M = fmaxf(m, ml1.x);
    float a0 = __builtin_exp2f(m - M), a1 = __builtin_exp2f(ml1.x - M);
    float inv = 1.0f / (lsum * a0 + ml1.y * a1);
    a0 *= inv; a1 *= inv;
    int rq = wq * 16 + l15;
#pragma unroll
    for (int df = 0; df < 4; ++df) {
      int byte = l15 * 256 + df * 64 + l4 * 16;
      f32x4 c1 = *(const f32x4*)(cbase + (byte ^ ((l15 & 7) << 4)));
      u16x4 h;
      h[0] = f2bf(ctx[df][0] * a0 + c1[0] * a1);
      h[1] = f2bf(ctx[df][1] * a0 + c1[1] * a1);
      h[2] = f2bf(ctx[df][2] * a0 + c1[2] * a1);
      h[3] = f2bf(ctx[df][3] * a0 + c1[3] * a1);
      int sbyte = rq * 128 + ((df * 32 + l4 * 8) ^ ((rq & 7) << 4));
      *(u16x4*)(lds + P_SA + sbyte) = h;
    }
  }
  asm volatile("s_waitcnt lgkmcnt(0)" ::: "memory");
  __builtin_amdgcn_sched_barrier(0);
  __builtin_amdgcn_s_barrier();

  // ---- phase 3: proj chunk loop ----
  // vmcnt FIFO: entry [bias(1), stB0(4), stB1(4)] -> c=0 vmcnt(4).
  // steady: [stores(c-2)(8), stage(c)(4), stores(c-1)(8), stage(c+1)(4)] -> vmcnt(12).
  // c=7: [stores5(8), stage7(4), stores6(8)] -> vmcnt(8).
#pragma unroll
  for (int c = 0; c < 8; ++c) {
    if (c == 0)      asm volatile("s_waitcnt vmcnt(4) lgkmcnt(0)" ::: "memory");
    else if (c == 7) asm volatile("s_waitcnt vmcnt(8) lgkmcnt(0)" ::: "memory");
    else             asm volatile("s_waitcnt vmcnt(12) lgkmcnt(0)" ::: "memory");
    __builtin_amdgcn_s_barrier();
    const char* bB = lds + P_WPT + (c & 1) * 32768;
    f32x4 acc[4][2] = {};
    __builtin_amdgcn_s_setprio(1);
#pragma unroll
    for (int kk = 0; kk < 2; ++kk) {
      int cb = kk * 64 + l4 * 16;
      bf16x8 af[4], bfr[2];
#pragma unroll
      for (int mm = 0; mm < 4; ++mm) {
        int r = mm * 16 + l15;
        af[mm] = *(const bf16x8*)(lds + P_SA + r * 128 + (cb ^ ((r & 7) << 4)));
      }
#pragma unroll
      for (int n = 0; n < 2; ++n) {
        int r = w * 32 + n * 16 + l15;
        bfr[n] = *(const bf16x8*)(bB + r * 128 + (cb ^ ((r & 7) << 4)));
      }
      // swapped: A=wpT-rows (out cols), B=ctx-rows (out rows)
#pragma unroll
      for (int mm = 0; mm < 4; ++mm)
#pragma unroll
        for (int n = 0; n < 2; ++n)
          acc[mm][n] = __builtin_amdgcn_mfma_f32_16x16x32_bf16(bfr[n], af[mm], acc[mm][n], 0, 0, 0);
    }
    __builtin_amdgcn_s_setprio(0);
#pragma unroll
    for (int mm = 0; mm < 4; ++mm)
#pragma unroll
      for (int n = 0; n < 2; ++n) {
        int grow = qbase + mm * 16 + l15;
        int gcol = c * 256 + w * 32 + n * 16 + l4 * 4;
        float4 bias = *(const float4*)(lds + P_BIAS + gcol * 4);  // lgkm, FIFO-safe
        float4 o;
        o.x = acc[mm][n][0] + bias.x; o.y = acc[mm][n][1] + bias.y;
        o.z = acc[mm][n][2] + bias.z; o.w = acc[mm][n][3] + bias.w;
        *(float4*)(out + ((size_t)bb * 2048 + grow) * 2048 + gcol) = o;
      }
    __builtin_amdgcn_s_barrier();        // all reads of buf (c&1) done
    if (c < 6) stageB(c + 2, c & 1);
  }
}

// ---------- launch ----------
extern "C" void kernel_launch(void* const* d_in, const int* in_sizes, int n_in,
                              void* d_out, int out_size, void* d_ws, size_t ws_size,
                              hipStream_t stream) {
  const float* x      = (const float*)d_in[0];
  const float* W_qkv  = (const float*)d_in[1];
  const float* b_qkv  = (const float*)d_in[2];
  const float* W_proj = (const float*)d_in[3];
  const float* b_proj = (const float*)d_in[4];
  float* out = (float*)d_out;

  unsigned short* ws   = (unsigned short*)d_ws;
  unsigned short* wqT  = ws;                                   // 192*2048
  unsigned short* wpT  = wqT + (size_t)192 * 2048;             // 2048*64
  unsigned short* qb   = wpT + (size_t)2048 * 64;              // 16384*64 (pre-scaled)
  unsigned short* kb   = qb  + (size_t)16384 * 64;
  unsigned short* vt   = kb  + (size_t)16384 * 64;             // [8][64][2048]

  k_trw<<<64, 256, 0, stream>>>(W_qkv, W_proj, wqT, wpT);
  k_qkv<<<256, 512, 0, stream>>>(x, wqT, b_qkv, qb, kb, vt);
  k_attnproj<<<dim3(32, 8), 512, 0, stream>>>(qb, kb, vt, wpT, b_proj, out);
}

// Round 10
// 92.247 us; speedup vs baseline: 1.2521x; 1.0534x over previous
//
#include <hip/hip_runtime.h>

// ---------- types ----------
typedef __bf16 bf16x8 __attribute__((ext_vector_type(8)));
typedef unsigned short u16x8 __attribute__((ext_vector_type(8)));
typedef unsigned short u16x4 __attribute__((ext_vector_type(4)));
typedef float  f32x4  __attribute__((ext_vector_type(4)));

#define QSCALE 0.1803368801111204f   // 0.125 * log2(e): S comes out in log2 domain

__device__ __forceinline__ unsigned short f2bf(float f) {
  unsigned int u = __float_as_uint(f);
  u = u + 0x7fffu + ((u >> 16) & 1u);   // RNE
  return (unsigned short)(u >> 16);
}

// global_load_lds, 16B per lane; LDS dest = wave-uniform base + lane*16
#define GLD16(src, dst)                                                        \
  __builtin_amdgcn_global_load_lds(                                            \
      (const __attribute__((address_space(1))) void*)(src),                    \
      (__attribute__((address_space(3))) void*)(dst), 16, 0, 0)

// All MFMA LDS tiles have 128-byte rows; swizzle: byte ^= (row&7)<<4 (both sides).

// ---------- 1. merged weight transposes (R7 verbatim) ----------
__global__ __launch_bounds__(256) void k_trw(const float* __restrict__ Wq,
                                             const float* __restrict__ Wp,
                                             unsigned short* __restrict__ wqT,
                                             unsigned short* __restrict__ wpT) {
  __shared__ float tile[64][193];
  const int t = threadIdx.x;
  if (blockIdx.x < 32) {
    const int k0 = blockIdx.x * 64;
#pragma unroll
    for (int i = 0; i < 12; ++i) {       // 64 rows x 48 float4
      int u = i * 256 + t;
      int row = u / 48, c4 = u % 48;
      float4 v = *(const float4*)(Wq + (size_t)(k0 + row) * 192 + c4 * 4);
      tile[row][c4 * 4 + 0] = v.x; tile[row][c4 * 4 + 1] = v.y;
      tile[row][c4 * 4 + 2] = v.z; tile[row][c4 * 4 + 3] = v.w;
    }
    __syncthreads();
#pragma unroll
    for (int i = 0; i < 6; ++i) {        // 192 cols x 8 u16x8
      int u = i * 256 + t;
      int c = u >> 3, k8 = (u & 7) * 8;
      u16x8 h;
#pragma unroll
      for (int j = 0; j < 8; ++j) h[j] = f2bf(tile[k8 + j][c]);
      *(u16x8*)(wqT + (size_t)c * 2048 + k0 + k8) = h;
    }
  } else {
    const int n0 = (blockIdx.x - 32) * 64;
#pragma unroll
    for (int i = 0; i < 4; ++i) {        // 64 d-rows x 16 float4
      int u = i * 256 + t;
      int dd = u >> 4, c4 = u & 15;
      float4 v = *(const float4*)(Wp + (size_t)dd * 2048 + n0 + c4 * 4);
      tile[dd][c4 * 4 + 0] = v.x; tile[dd][c4 * 4 + 1] = v.y;
      tile[dd][c4 * 4 + 2] = v.z; tile[dd][c4 * 4 + 3] = v.w;
    }
    __syncthreads();
#pragma unroll
    for (int i = 0; i < 2; ++i) {        // 64 n-rows x 8 u16x8
      int u = i * 256 + t;
      int n = u >> 3, d8 = (u & 7) * 8;
      u16x8 h;
      h[0] = f2bf(tile[d8 + 0][n]); h[1] = f2bf(tile[d8 + 1][n]);
      h[2] = f2bf(tile[d8 + 2][n]); h[3] = f2bf(tile[d8 + 3][n]);
      h[4] = f2bf(tile[d8 + 4][n]); h[5] = f2bf(tile[d8 + 5][n]);
      h[6] = f2bf(tile[d8 + 6][n]); h[7] = f2bf(tile[d8 + 7][n]);
      *(u16x8*)(wpT + (size_t)(n0 + n) * 64 + d8) = h;
    }
  }
}

// ---------- 2. fused QKV GEMM: [16384,2048] x [2048,192]  (R7 verbatim) ----------
__global__ __launch_bounds__(512) void k_qkv(const float* __restrict__ x,
                                             const unsigned short* __restrict__ wqT,
                                             const float* __restrict__ b_qkv,
                                             unsigned short* __restrict__ qb,
                                             unsigned short* __restrict__ kb,
                                             unsigned short* __restrict__ vt) {
  __shared__ __align__(16) char lds[65536];  // sA[d]: d*8192 ; sB[d]: 16384+d*24576
  const int t = threadIdx.x;
  const int lane = t & 63, w = t >> 6;
  const int l15 = lane & 15, l4 = lane >> 4;
  const int wm = w >> 2, wn = w & 3;
  const int m0 = blockIdx.x * 64;

  const int arow = t >> 3;            // 0..63
  const int akc  = (t & 7) * 8;       // 0..56
  const float* xrow = x + (size_t)(m0 + arow) * 2048 + akc;
  const int aoff = arow * 128 + ((akc * 2) ^ ((arow & 7) << 4));

  f32x4 acc[2][3] = {};
  float4 xa0_0, xa1_0, xa0_1, xa1_1;   // 2-deep x prefetch, parity = kt&1

  auto issueA_0 = [&](int kt) {
    xa0_0 = *(const float4*)(xrow + kt * 64);
    xa1_0 = *(const float4*)(xrow + kt * 64 + 4);
  };
  auto issueA_1 = [&](int kt) {
    xa0_1 = *(const float4*)(xrow + kt * 64);
    xa1_1 = *(const float4*)(xrow + kt * 64 + 4);
  };
  auto writeA_0 = [&]() {
    u16x8 h;
    h[0] = f2bf(xa0_0.x); h[1] = f2bf(xa0_0.y); h[2] = f2bf(xa0_0.z); h[3] = f2bf(xa0_0.w);
    h[4] = f2bf(xa1_0.x); h[5] = f2bf(xa1_0.y); h[6] = f2bf(xa1_0.z); h[7] = f2bf(xa1_0.w);
    *(u16x8*)(lds + 0 * 8192 + aoff) = h;
  };
  auto writeA_1 = [&]() {
    u16x8 h;
    h[0] = f2bf(xa0_1.x); h[1] = f2bf(xa0_1.y); h[2] = f2bf(xa0_1.z); h[3] = f2bf(xa0_1.w);
    h[4] = f2bf(xa1_1.x); h[5] = f2bf(xa1_1.y); h[6] = f2bf(xa1_1.z); h[7] = f2bf(xa1_1.w);
    *(u16x8*)(lds + 1 * 8192 + aoff) = h;
  };
  auto stageB = [&](int kt, int d) {
    char* bbase = lds + 16384 + d * 24576;
#pragma unroll
    for (int p = 0; p < 3; ++p) {
      int L = p * 8192 + (w << 10) + (lane << 4);
      int row = L >> 7;
      int cb = (L & 127) ^ ((row & 7) << 4);
      GLD16((const char*)wqT + (size_t)row * 4096 + kt * 128 + cb,
            bbase + p * 8192 + (w << 10));
    }
  };
  auto compute = [&](int d) {
    const char* aB = lds + d * 8192;
    const char* bB = lds + 16384 + d * 24576;
    __builtin_amdgcn_s_setprio(1);
#pragma unroll
    for (int kk = 0; kk < 2; ++kk) {
      int cb = kk * 64 + l4 * 16;
      bf16x8 af[2], bfr[3];
#pragma unroll
      for (int m = 0; m < 2; ++m) {
        int r = wm * 32 + m * 16 + l15;
        af[m] = *(const bf16x8*)(aB + r * 128 + (cb ^ ((r & 7) << 4)));
      }
#pragma unroll
      for (int n = 0; n < 3; ++n) {
        int r = wn * 48 + n * 16 + l15;
        bfr[n] = *(const bf16x8*)(bB + r * 128 + (cb ^ ((r & 7) << 4)));
      }
#pragma unroll
      for (int m = 0; m < 2; ++m)
#pragma unroll
        for (int n = 0; n < 3; ++n)
          acc[m][n] = __builtin_amdgcn_mfma_f32_16x16x32_bf16(af[m], bfr[n], acc[m][n], 0, 0, 0);
    }
    __builtin_amdgcn_s_setprio(0);
  };

#define QKV_STEP(n, P, DOI, DOS, W)                                    \
  {                                                                    \
    writeA_##P();                                                      \
    if (DOI) issueA_##P((n) + 2);                                      \
    if (DOS) stageB((n) + 1, (P) ^ 1);                                 \
    asm volatile("s_waitcnt vmcnt(" W ") lgkmcnt(0)" ::: "memory");    \
    __builtin_amdgcn_s_barrier();                                      \
    compute(P);                                                        \
    __builtin_amdgcn_s_barrier();                                      \
  }

  issueA_0(0); issueA_1(1); stageB(0, 0);
  for (int kt = 0; kt < 30; kt += 2) {
    QKV_STEP(kt,     0, true, true, "5");
    QKV_STEP(kt + 1, 1, true, true, "5");
  }
  QKV_STEP(30, 0, false, true,  "5");
  QKV_STEP(31, 1, false, false, "0");
#undef QKV_STEP

  // epilogue: C/D layout col=lane&15, row=(lane>>4)*4+reg
#pragma unroll
  for (int m = 0; m < 2; ++m)
#pragma unroll
    for (int n = 0; n < 3; ++n) {
      int c = wn * 48 + n * 16 + l15;   // 0..191
      int j = c >> 6, cc = c & 63;
      float bias = b_qkv[c];
      int grow0 = m0 + wm * 32 + m * 16 + l4 * 4;
      if (j == 0) {
#pragma unroll
        for (int r = 0; r < 4; ++r)
          qb[(size_t)(grow0 + r) * 64 + cc] = f2bf((acc[m][n][r] + bias) * QSCALE);
      } else if (j == 1) {
#pragma unroll
        for (int r = 0; r < 4; ++r)
          kb[(size_t)(grow0 + r) * 64 + cc] = f2bf(acc[m][n][r] + bias);
      } else {            // v transposed: [b][64][2048]
        int bbv = grow0 >> 11, nn0 = grow0 & 2047;
        u16x4 h;
        h[0] = f2bf(acc[m][n][0] + bias); h[1] = f2bf(acc[m][n][1] + bias);
        h[2] = f2bf(acc[m][n][2] + bias); h[3] = f2bf(acc[m][n][3] + bias);
        *(u16x4*)(vt + ((size_t)bbv * 64 + cc) * 2048 + nn0) = h;
      }
    }
}

// ---------- 3. fused attention + proj (R7 pipeline; XCD-batch affinity) ----------
// flat grid 256: XCD = lin%8 -> bb = lin&7 so each XCD reads ONE batch's K/V
// (L2-resident, ~28 MB less HBM fetch). qtile = lin>>3. Pure index remap.
#define P_CTX1 0          // [0, 16K): half1 ctx exchange (reuses K/V region)
#define P_ML1  16384      // [16K, 16K+512)
#define P_SA   24576      // [24K, 32K)
#define P_BIAS 32768      // [32K, 40K)   (written only AFTER phase 1 -- safe)
#define P_WPT  40960      // [40K, 104K): wpT dbuf 2 x 32K
__global__ __launch_bounds__(512) void k_attnproj(const unsigned short* __restrict__ qb,
                                                  const unsigned short* __restrict__ kb,
                                                  const unsigned short* __restrict__ vt,
                                                  const unsigned short* __restrict__ wpT,
                                                  const float* __restrict__ b_proj,
                                                  float* __restrict__ out) {
  __shared__ __align__(16) char lds[106496];
  const int t = threadIdx.x;
  const int lane = t & 63, w = t >> 6;
  const int l15 = lane & 15, l4 = lane >> 4;
  const int wq = w & 3, wh = w >> 2;
  const int lin = blockIdx.x;
  const int bb = lin & 7;              // batch-per-XCD
  const int qbase = (lin >> 3) * 64;
  const int q0 = qbase + wq * 16;
  const int kt0 = wh * 16;
  const unsigned short* qrow = qb + ((size_t)bb * 2048 + q0 + l15) * 64;
  bf16x8 aq[2];
  aq[0] = *(const bf16x8*)(qrow + l4 * 8);       // B-frag: col=l15(q), k=(l>>4)*8+j
  aq[1] = *(const bf16x8*)(qrow + 32 + l4 * 8);
  f32x4 ctx[4] = {};                              // ctx^T: q=l15, d=df*16+l4*4+r
  float m = -1e30f, lsum = 0.f;
  const char* kBase = (const char*)kb + (size_t)bb * 2048 * 128;
  const char* vBase = (const char*)vt + (size_t)bb * 64 * 4096;
  const int srcA = ((l4 & 1) << 5) | l15;
  const int srcB = srcA + 16;
  const bool hi = (l4 >> 1) & 1;

  auto stage = [&](int kt, int d) {
#pragma unroll
    for (int p = 0; p < 2; ++p) {
      int L = p * 4096 + (wq << 10) + (lane << 4);
      int row = L >> 7;
      int cb = (L & 127) ^ ((row & 7) << 4);
      GLD16(kBase + (size_t)(kt * 64 + row) * 128 + cb,
            lds + wh * 32768 + d * 8192 + p * 4096 + (wq << 10));
      GLD16(vBase + (size_t)row * 4096 + kt * 128 + cb,
            lds + wh * 32768 + 16384 + d * 8192 + p * 4096 + (wq << 10));
    }
  };
  auto stageB = [&](int c, int dd) {      // wpT rows [c*256, +256) -> 32KB
    char* bbase = lds + P_WPT + dd * 32768;
#pragma unroll
    for (int p = 0; p < 4; ++p) {         // 4 x (512 threads x 16B)
      int L = p * 8192 + t * 16;
      int row = L >> 7;
      int cb = (L & 127) ^ ((row & 7) << 4);
      GLD16((const char*)wpT + (size_t)(c * 256 + row) * 128 + cb,
            bbase + p * 8192 + (w << 10));
    }
  };

  // ---- phase 1 ----
  stage(kt0, 0);
  int d = 0;
  for (int kt = 0; kt < 16; ++kt) {
    if (kt < 15) {
      stage(kt0 + kt + 1, d ^ 1);
      asm volatile("s_waitcnt vmcnt(4)" ::: "memory");   // drains tile kt, keeps prefetch
    } else {
      asm volatile("s_waitcnt vmcnt(0)" ::: "memory");
    }
    __builtin_amdgcn_s_barrier();
    const char* sK = lds + wh * 32768 + d * 8192;
    const char* sV = lds + wh * 32768 + 16384 + d * 8192;
    // S^T = K Q^T : s[mf] holds q=l15, kv = mf*16 + l4*4 + r  (log2 domain)
    f32x4 s[4] = {};
    __builtin_amdgcn_s_setprio(1);
#pragma unroll
    for (int kk = 0; kk < 2; ++kk) {
      int cb = kk * 64 + l4 * 16;
#pragma unroll
      for (int mf = 0; mf < 4; ++mf) {
        int r = mf * 16 + l15;
        bf16x8 kf = *(const bf16x8*)(sK + r * 128 + (cb ^ ((r & 7) << 4)));
        s[mf] = __builtin_amdgcn_mfma_f32_16x16x32_bf16(kf, aq[kk], s[mf], 0, 0, 0);
      }
    }
    __builtin_amdgcn_s_setprio(0);
    // 16-value max via max3-shaped tree (clang fuses nested fmaxf to v_max3)
    float t0 = fmaxf(fmaxf(s[0][0], s[0][1]), s[0][2]);
    float t1 = fmaxf(fmaxf(s[0][3], s[1][0]), s[1][1]);
    float t2 = fmaxf(fmaxf(s[1][2], s[1][3]), s[2][0]);
    float t3 = fmaxf(fmaxf(s[2][1], s[2][2]), s[2][3]);
    float t4 = fmaxf(fmaxf(s[3][0], s[3][1]), s[3][2]);
    float pm = fmaxf(fmaxf(fmaxf(t0, t1), t2), fmaxf(fmaxf(t3, t4), s[3][3]));
    pm = fmaxf(pm, __shfl_xor(pm, 16));
    pm = fmaxf(pm, __shfl_xor(pm, 32));
    if (!__all(pm <= m + 11.5f)) {     // T13 defer-max (log2 domain)
      float mn = fmaxf(m, pm);
      float al = __builtin_exp2f(m - mn);
      m = mn; lsum *= al;
#pragma unroll
      for (int df = 0; df < 4; ++df)
#pragma unroll
        for (int r = 0; r < 4; ++r) ctx[df][r] *= al;
    }
    float lp = 0.f;
#pragma unroll
    for (int mf = 0; mf < 4; ++mf)
#pragma unroll
      for (int r = 0; r < 4; ++r) {
        float p = __builtin_exp2f(s[mf][r] - m);
        s[mf][r] = p;
        lp += p;
      }
    lsum += lp;
    unsigned int pk[4][2];
#pragma unroll
    for (int mf = 0; mf < 4; ++mf) {
      asm("v_cvt_pk_bf16_f32 %0, %1, %2" : "=v"(pk[mf][0]) : "v"(s[mf][0]), "v"(s[mf][1]));
      asm("v_cvt_pk_bf16_f32 %0, %1, %2" : "=v"(pk[mf][1]) : "v"(s[mf][2]), "v"(s[mf][3]));
    }
    // ctx^T += V^T P^T
#pragma unroll
    for (int kk = 0; kk < 2; ++kk) {
      unsigned int q00 = __shfl((int)pk[2 * kk][0], srcA);
      unsigned int q10 = __shfl((int)pk[2 * kk + 1][0], srcA);
      unsigned int q01 = __shfl((int)pk[2 * kk][1], srcA);
      unsigned int q11 = __shfl((int)pk[2 * kk + 1][1], srcA);
      unsigned int r00 = __shfl((int)pk[2 * kk][0], srcB);
      unsigned int r10 = __shfl((int)pk[2 * kk + 1][0], srcB);
      unsigned int r01 = __shfl((int)pk[2 * kk][1], srcB);
      unsigned int r11 = __shfl((int)pk[2 * kk + 1][1], srcB);
      uint4 uu;
      uu.x = hi ? q10 : q00;
      uu.y = hi ? q11 : q01;
      uu.z = hi ? r10 : r00;
      uu.w = hi ? r11 : r01;
      bf16x8 pfrag = *(bf16x8*)&uu;
      int cb = kk * 64 + l4 * 16;
      __builtin_amdgcn_s_setprio(1);
#pragma unroll
      for (int df = 0; df < 4; ++df) {
        int rv = df * 16 + l15;
        bf16x8 vf = *(const bf16x8*)(sV + rv * 128 + (cb ^ ((rv & 7) << 4)));
        ctx[df] = __builtin_amdgcn_mfma_f32_16x16x32_bf16(vf, pfrag, ctx[df], 0, 0, 0);
      }
      __builtin_amdgcn_s_setprio(0);
    }
    __builtin_amdgcn_s_barrier();
    d ^= 1;
  }
  lsum += __shfl_xor(lsum, 16);
  lsum += __shfl_xor(lsum, 32);

  // ---- phase 2: prefetch proj operands (K/V region now dead), then LDS combine ----
  GLD16((const char*)b_proj + (w << 10) + (lane << 4), lds + P_BIAS + (w << 10));
  stageB(0, 0); stageB(1, 1);

  if (wh == 1) {                         // deposit half1 state
    char* cbase = lds + P_CTX1 + (wq << 12);
#pragma unroll
    for (int df = 0; df < 4; ++df) {
      int byte = l15 * 256 + df * 64 + l4 * 16;
      *(f32x4*)(cbase + (byte ^ ((l15 & 7) << 4))) = ctx[df];
    }
    if (l4 == 0)
      *(float2*)(lds + P_ML1 + wq * 128 + l15 * 8) = make_float2(m, lsum);
  }
  asm volatile("s_waitcnt lgkmcnt(0)" ::: "memory");
  __builtin_amdgcn_sched_barrier(0);
  __builtin_amdgcn_s_barrier();
  if (wh == 0) {                         // merge halves -> sA bf16 [64][64] swizzled
    char* cbase = lds + P_CTX1 + (wq << 12);
    float2 ml1 = *(const float2*)(lds + P_ML1 + wq * 128 + l15 * 8);
    float M = fmaxf(m, ml1.x);
    float a0 = __builtin_exp2f(m - M), a1 = __builtin_exp2f(ml1.x - M);
    float inv = 1.0f / (lsum * a0 + ml1.y * a1);
    a0 *= inv; a1 *= inv;
    int rq = wq * 16 + l15;
#pragma unroll
    for (int df = 0; df < 4; ++df) {
      int byte = l15 * 256 + df * 64 + l4 * 16;
      f32x4 c1 = *(const f32x4*)(cbase + (byte ^ ((l15 & 7) << 4)));
      u16x4 h;
      h[0] = f2bf(ctx[df][0] * a0 + c1[0] * a1);
      h[1] = f2bf(ctx[df][1] * a0 + c1[1] * a1);
      h[2] = f2bf(ctx[df][2] * a0 + c1[2] * a1);
      h[3] = f2bf(ctx[df][3] * a0 + c1[3] * a1);
      int sbyte = rq * 128 + ((df * 32 + l4 * 8) ^ ((rq & 7) << 4));
      *(u16x4*)(lds + P_SA + sbyte) = h;
    }
  }
  asm volatile("s_waitcnt lgkmcnt(0)" ::: "memory");
  __builtin_amdgcn_sched_barrier(0);
  __builtin_amdgcn_s_barrier();

  // ---- phase 3: proj chunk loop ----
  // vmcnt FIFO: entry [bias(1), stB0(4), stB1(4)] -> c=0 vmcnt(4).
  // steady: [stores(c-2)(8), stage(c)(4), stores(c-1)(8), stage(c+1)(4)] -> vmcnt(12).
  // c=7: [stores5(8), stage7(4), stores6(8)] -> vmcnt(8).
#pragma unroll
  for (int c = 0; c < 8; ++c) {
    if (c == 0)      asm volatile("s_waitcnt vmcnt(4) lgkmcnt(0)" ::: "memory");
    else if (c == 7) asm volatile("s_waitcnt vmcnt(8) lgkmcnt(0)" ::: "memory");
    else             asm volatile("s_waitcnt vmcnt(12) lgkmcnt(0)" ::: "memory");
    __builtin_amdgcn_s_barrier();
    const char* bB = lds + P_WPT + (c & 1) * 32768;
    f32x4 acc[4][2] = {};
    __builtin_amdgcn_s_setprio(1);
#pragma unroll
    for (int kk = 0; kk < 2; ++kk) {
      int cb = kk * 64 + l4 * 16;
      bf16x8 af[4], bfr[2];
#pragma unroll
      for (int mm = 0; mm < 4; ++mm) {
        int r = mm * 16 + l15;
        af[mm] = *(const bf16x8*)(lds + P_SA + r * 128 + (cb ^ ((r & 7) << 4)));
      }
#pragma unroll
      for (int n = 0; n < 2; ++n) {
        int r = w * 32 + n * 16 + l15;
        bfr[n] = *(const bf16x8*)(bB + r * 128 + (cb ^ ((r & 7) << 4)));
      }
      // swapped: A=wpT-rows (out cols), B=ctx-rows (out rows)
#pragma unroll
      for (int mm = 0; mm < 4; ++mm)
#pragma unroll
        for (int n = 0; n < 2; ++n)
          acc[mm][n] = __builtin_amdgcn_mfma_f32_16x16x32_bf16(bfr[n], af[mm], acc[mm][n], 0, 0, 0);
    }
    __builtin_amdgcn_s_setprio(0);
#pragma unroll
    for (int mm = 0; mm < 4; ++mm)
#pragma unroll
      for (int n = 0; n < 2; ++n) {
        int grow = qbase + mm * 16 + l15;
        int gcol = c * 256 + w * 32 + n * 16 + l4 * 4;
        float4 bias = *(const float4*)(lds + P_BIAS + gcol * 4);  // lgkm, FIFO-safe
        float4 o;
        o.x = acc[mm][n][0] + bias.x; o.y = acc[mm][n][1] + bias.y;
        o.z = acc[mm][n][2] + bias.z; o.w = acc[mm][n][3] + bias.w;
        *(float4*)(out + ((size_t)bb * 2048 + grow) * 2048 + gcol) = o;
      }
    __builtin_amdgcn_s_barrier();        // all reads of buf (c&1) done
    if (c < 6) stageB(c + 2, c & 1);
  }
}

// ---------- launch ----------
extern "C" void kernel_launch(void* const* d_in, const int* in_sizes, int n_in,
                              void* d_out, int out_size, void* d_ws, size_t ws_size,
                              hipStream_t stream) {
  const float* x      = (const float*)d_in[0];
  const float* W_qkv  = (const float*)d_in[1];
  const float* b_qkv  = (const float*)d_in[2];
  const float* W_proj = (const float*)d_in[3];
  const float* b_proj = (const float*)d_in[4];
  float* out = (float*)d_out;

  unsigned short* ws   = (unsigned short*)d_ws;
  unsigned short* wqT  = ws;                                   // 192*2048
  unsigned short* wpT  = wqT + (size_t)192 * 2048;             // 2048*64
  unsigned short* qb   = wpT + (size_t)2048 * 64;              // 16384*64 (pre-scaled)
  unsigned short* kb   = qb  + (size_t)16384 * 64;
  unsigned short* vt   = kb  + (size_t)16384 * 64;             // [8][64][2048]

  k_trw<<<64, 256, 0, stream>>>(W_qkv, W_proj, wqT, wpT);
  k_qkv<<<256, 512, 0, stream>>>(x, wqT, b_qkv, qb, kb, vt);
  k_attnproj<<<256, 512, 0, stream>>>(qb, kb, vt, wpT, b_proj, out);
}

// Round 11
// 91.171 us; speedup vs baseline: 1.2669x; 1.0118x over previous
//
#include <hip/hip_runtime.h>

// ---------- types ----------
typedef __bf16 bf16x8 __attribute__((ext_vector_type(8)));
typedef unsigned short u16x8 __attribute__((ext_vector_type(8)));
typedef unsigned short u16x4 __attribute__((ext_vector_type(4)));
typedef float  f32x4  __attribute__((ext_vector_type(4)));

#define QSCALE 0.1803368801111204f   // 0.125 * log2(e): S comes out in log2 domain

__device__ __forceinline__ unsigned short f2bf(float f) {
  unsigned int u = __float_as_uint(f);
  u = u + 0x7fffu + ((u >> 16) & 1u);   // RNE
  return (unsigned short)(u >> 16);
}

// global_load_lds, 16B per lane; LDS dest = wave-uniform base + lane*16
#define GLD16(src, dst)                                                        \
  __builtin_amdgcn_global_load_lds(                                            \
      (const __attribute__((address_space(1))) void*)(src),                    \
      (__attribute__((address_space(3))) void*)(dst), 16, 0, 0)

// All MFMA LDS tiles have 128-byte rows; swizzle: byte ^= (row&7)<<4 (both sides).

// ---------- 1. merged weight transposes (R10 verbatim) ----------
__global__ __launch_bounds__(256) void k_trw(const float* __restrict__ Wq,
                                             const float* __restrict__ Wp,
                                             unsigned short* __restrict__ wqT,
                                             unsigned short* __restrict__ wpT) {
  __shared__ float tile[64][193];
  const int t = threadIdx.x;
  if (blockIdx.x < 32) {
    const int k0 = blockIdx.x * 64;
#pragma unroll
    for (int i = 0; i < 12; ++i) {       // 64 rows x 48 float4
      int u = i * 256 + t;
      int row = u / 48, c4 = u % 48;
      float4 v = *(const float4*)(Wq + (size_t)(k0 + row) * 192 + c4 * 4);
      tile[row][c4 * 4 + 0] = v.x; tile[row][c4 * 4 + 1] = v.y;
      tile[row][c4 * 4 + 2] = v.z; tile[row][c4 * 4 + 3] = v.w;
    }
    __syncthreads();
#pragma unroll
    for (int i = 0; i < 6; ++i) {        // 192 cols x 8 u16x8
      int u = i * 256 + t;
      int c = u >> 3, k8 = (u & 7) * 8;
      u16x8 h;
#pragma unroll
      for (int j = 0; j < 8; ++j) h[j] = f2bf(tile[k8 + j][c]);
      *(u16x8*)(wqT + (size_t)c * 2048 + k0 + k8) = h;
    }
  } else {
    const int n0 = (blockIdx.x - 32) * 64;
#pragma unroll
    for (int i = 0; i < 4; ++i) {        // 64 d-rows x 16 float4
      int u = i * 256 + t;
      int dd = u >> 4, c4 = u & 15;
      float4 v = *(const float4*)(Wp + (size_t)dd * 2048 + n0 + c4 * 4);
      tile[dd][c4 * 4 + 0] = v.x; tile[dd][c4 * 4 + 1] = v.y;
      tile[dd][c4 * 4 + 2] = v.z; tile[dd][c4 * 4 + 3] = v.w;
    }
    __syncthreads();
#pragma unroll
    for (int i = 0; i < 2; ++i) {        // 64 n-rows x 8 u16x8
      int u = i * 256 + t;
      int n = u >> 3, d8 = (u & 7) * 8;
      u16x8 h;
      h[0] = f2bf(tile[d8 + 0][n]); h[1] = f2bf(tile[d8 + 1][n]);
      h[2] = f2bf(tile[d8 + 2][n]); h[3] = f2bf(tile[d8 + 3][n]);
      h[4] = f2bf(tile[d8 + 4][n]); h[5] = f2bf(tile[d8 + 5][n]);
      h[6] = f2bf(tile[d8 + 6][n]); h[7] = f2bf(tile[d8 + 7][n]);
      *(u16x8*)(wpT + (size_t)(n0 + n) * 64 + d8) = h;
    }
  }
}

// ---------- 2. fused QKV GEMM: [16384,2048] x [2048,192]  (R10 verbatim) ----------
__global__ __launch_bounds__(512) void k_qkv(const float* __restrict__ x,
                                             const unsigned short* __restrict__ wqT,
                                             const float* __restrict__ b_qkv,
                                             unsigned short* __restrict__ qb,
                                             unsigned short* __restrict__ kb,
                                             unsigned short* __restrict__ vt) {
  __shared__ __align__(16) char lds[65536];  // sA[d]: d*8192 ; sB[d]: 16384+d*24576
  const int t = threadIdx.x;
  const int lane = t & 63, w = t >> 6;
  const int l15 = lane & 15, l4 = lane >> 4;
  const int wm = w >> 2, wn = w & 3;
  const int m0 = blockIdx.x * 64;

  const int arow = t >> 3;            // 0..63
  const int akc  = (t & 7) * 8;       // 0..56
  const float* xrow = x + (size_t)(m0 + arow) * 2048 + akc;
  const int aoff = arow * 128 + ((akc * 2) ^ ((arow & 7) << 4));

  f32x4 acc[2][3] = {};
  float4 xa0_0, xa1_0, xa0_1, xa1_1;   // 2-deep x prefetch, parity = kt&1

  auto issueA_0 = [&](int kt) {
    xa0_0 = *(const float4*)(xrow + kt * 64);
    xa1_0 = *(const float4*)(xrow + kt * 64 + 4);
  };
  auto issueA_1 = [&](int kt) {
    xa0_1 = *(const float4*)(xrow + kt * 64);
    xa1_1 = *(const float4*)(xrow + kt * 64 + 4);
  };
  auto writeA_0 = [&]() {
    u16x8 h;
    h[0] = f2bf(xa0_0.x); h[1] = f2bf(xa0_0.y); h[2] = f2bf(xa0_0.z); h[3] = f2bf(xa0_0.w);
    h[4] = f2bf(xa1_0.x); h[5] = f2bf(xa1_0.y); h[6] = f2bf(xa1_0.z); h[7] = f2bf(xa1_0.w);
    *(u16x8*)(lds + 0 * 8192 + aoff) = h;
  };
  auto writeA_1 = [&]() {
    u16x8 h;
    h[0] = f2bf(xa0_1.x); h[1] = f2bf(xa0_1.y); h[2] = f2bf(xa0_1.z); h[3] = f2bf(xa0_1.w);
    h[4] = f2bf(xa1_1.x); h[5] = f2bf(xa1_1.y); h[6] = f2bf(xa1_1.z); h[7] = f2bf(xa1_1.w);
    *(u16x8*)(lds + 1 * 8192 + aoff) = h;
  };
  auto stageB = [&](int kt, int d) {
    char* bbase = lds + 16384 + d * 24576;
#pragma unroll
    for (int p = 0; p < 3; ++p) {
      int L = p * 8192 + (w << 10) + (lane << 4);
      int row = L >> 7;
      int cb = (L & 127) ^ ((row & 7) << 4);
      GLD16((const char*)wqT + (size_t)row * 4096 + kt * 128 + cb,
            bbase + p * 8192 + (w << 10));
    }
  };
  auto compute = [&](int d) {
    const char* aB = lds + d * 8192;
    const char* bB = lds + 16384 + d * 24576;
    __builtin_amdgcn_s_setprio(1);
#pragma unroll
    for (int kk = 0; kk < 2; ++kk) {
      int cb = kk * 64 + l4 * 16;
      bf16x8 af[2], bfr[3];
#pragma unroll
      for (int m = 0; m < 2; ++m) {
        int r = wm * 32 + m * 16 + l15;
        af[m] = *(const bf16x8*)(aB + r * 128 + (cb ^ ((r & 7) << 4)));
      }
#pragma unroll
      for (int n = 0; n < 3; ++n) {
        int r = wn * 48 + n * 16 + l15;
        bfr[n] = *(const bf16x8*)(bB + r * 128 + (cb ^ ((r & 7) << 4)));
      }
#pragma unroll
      for (int m = 0; m < 2; ++m)
#pragma unroll
        for (int n = 0; n < 3; ++n)
          acc[m][n] = __builtin_amdgcn_mfma_f32_16x16x32_bf16(af[m], bfr[n], acc[m][n], 0, 0, 0);
    }
    __builtin_amdgcn_s_setprio(0);
  };

#define QKV_STEP(n, P, DOI, DOS, W)                                    \
  {                                                                    \
    writeA_##P();                                                      \
    if (DOI) issueA_##P((n) + 2);                                      \
    if (DOS) stageB((n) + 1, (P) ^ 1);                                 \
    asm volatile("s_waitcnt vmcnt(" W ") lgkmcnt(0)" ::: "memory");    \
    __builtin_amdgcn_s_barrier();                                      \
    compute(P);                                                        \
    __builtin_amdgcn_s_barrier();                                      \
  }

  issueA_0(0); issueA_1(1); stageB(0, 0);
  for (int kt = 0; kt < 30; kt += 2) {
    QKV_STEP(kt,     0, true, true, "5");
    QKV_STEP(kt + 1, 1, true, true, "5");
  }
  QKV_STEP(30, 0, false, true,  "5");
  QKV_STEP(31, 1, false, false, "0");
#undef QKV_STEP

  // epilogue: C/D layout col=lane&15, row=(lane>>4)*4+reg
#pragma unroll
  for (int m = 0; m < 2; ++m)
#pragma unroll
    for (int n = 0; n < 3; ++n) {
      int c = wn * 48 + n * 16 + l15;   // 0..191
      int j = c >> 6, cc = c & 63;
      float bias = b_qkv[c];
      int grow0 = m0 + wm * 32 + m * 16 + l4 * 4;
      if (j == 0) {
#pragma unroll
        for (int r = 0; r < 4; ++r)
          qb[(size_t)(grow0 + r) * 64 + cc] = f2bf((acc[m][n][r] + bias) * QSCALE);
      } else if (j == 1) {
#pragma unroll
        for (int r = 0; r < 4; ++r)
          kb[(size_t)(grow0 + r) * 64 + cc] = f2bf(acc[m][n][r] + bias);
      } else {            // v transposed: [b][64][2048]
        int bbv = grow0 >> 11, nn0 = grow0 & 2047;
        u16x4 h;
        h[0] = f2bf(acc[m][n][0] + bias); h[1] = f2bf(acc[m][n][1] + bias);
        h[2] = f2bf(acc[m][n][2] + bias); h[3] = f2bf(acc[m][n][3] + bias);
        *(u16x4*)(vt + ((size_t)bbv * 64 + cc) * 2048 + nn0) = h;
      }
    }
}

// ---------- 3. fused attention + proj, XCD-batch affinity, 72KB LDS (2 blk/CU) ----------
// flat grid 256: bb = lin&7 (batch-per-XCD), qtile = lin>>3.
// wpT staged in 128-row chunks (16KB) x 2 dbuf -> total LDS 72KB -> 2 blocks/CU.
#define P_CTX1 0          // [0, 16K): half1 ctx exchange (reuses K/V region)
#define P_ML1  16384      // [16K, 16K+512)
#define P_SA   24576      // [24K, 32K)
#define P_BIAS 32768      // [32K, 40K)   (written only AFTER phase 1 -- safe)
#define P_WPT  40960      // [40K, 72K): wpT dbuf 2 x 16K
__global__ __launch_bounds__(512) void k_attnproj(const unsigned short* __restrict__ qb,
                                                  const unsigned short* __restrict__ kb,
                                                  const unsigned short* __restrict__ vt,
                                                  const unsigned short* __restrict__ wpT,
                                                  const float* __restrict__ b_proj,
                                                  float* __restrict__ out) {
  __shared__ __align__(16) char lds[73728];
  const int t = threadIdx.x;
  const int lane = t & 63, w = t >> 6;
  const int l15 = lane & 15, l4 = lane >> 4;
  const int wq = w & 3, wh = w >> 2;
  const int lin = blockIdx.x;
  const int bb = lin & 7;              // batch-per-XCD
  const int qbase = (lin >> 3) * 64;
  const int q0 = qbase + wq * 16;
  const int kt0 = wh * 16;
  const unsigned short* qrow = qb + ((size_t)bb * 2048 + q0 + l15) * 64;
  bf16x8 aq[2];
  aq[0] = *(const bf16x8*)(qrow + l4 * 8);       // B-frag: col=l15(q), k=(l>>4)*8+j
  aq[1] = *(const bf16x8*)(qrow + 32 + l4 * 8);
  f32x4 ctx[4] = {};                              // ctx^T: q=l15, d=df*16+l4*4+r
  float m = -1e30f, lsum = 0.f;
  const char* kBase = (const char*)kb + (size_t)bb * 2048 * 128;
  const char* vBase = (const char*)vt + (size_t)bb * 64 * 4096;
  const int srcA = ((l4 & 1) << 5) | l15;
  const int srcB = srcA + 16;
  const bool hi = (l4 >> 1) & 1;

  auto stage = [&](int kt, int d) {
#pragma unroll
    for (int p = 0; p < 2; ++p) {
      int L = p * 4096 + (wq << 10) + (lane << 4);
      int row = L >> 7;
      int cb = (L & 127) ^ ((row & 7) << 4);
      GLD16(kBase + (size_t)(kt * 64 + row) * 128 + cb,
            lds + wh * 32768 + d * 8192 + p * 4096 + (wq << 10));
      GLD16(vBase + (size_t)row * 4096 + kt * 128 + cb,
            lds + wh * 32768 + 16384 + d * 8192 + p * 4096 + (wq << 10));
    }
  };
  auto stageB = [&](int c, int dd) {      // wpT rows [c*128, +128) -> 16KB
    char* bbase = lds + P_WPT + dd * 16384;
#pragma unroll
    for (int p = 0; p < 2; ++p) {         // 2 x (512 threads x 16B)
      int L = p * 8192 + t * 16;
      int row = L >> 7;
      int cb = (L & 127) ^ ((row & 7) << 4);
      GLD16((const char*)wpT + (size_t)(c * 128 + row) * 128 + cb,
            bbase + p * 8192 + (w << 10));
    }
  };

  // ---- phase 1 ----
  stage(kt0, 0);
  int d = 0;
  for (int kt = 0; kt < 16; ++kt) {
    if (kt < 15) {
      stage(kt0 + kt + 1, d ^ 1);
      asm volatile("s_waitcnt vmcnt(4)" ::: "memory");   // drains tile kt, keeps prefetch
    } else {
      asm volatile("s_waitcnt vmcnt(0)" ::: "memory");
    }
    __builtin_amdgcn_s_barrier();
    const char* sK = lds + wh * 32768 + d * 8192;
    const char* sV = lds + wh * 32768 + 16384 + d * 8192;
    // S^T = K Q^T : s[mf] holds q=l15, kv = mf*16 + l4*4 + r  (log2 domain)
    f32x4 s[4] = {};
    __builtin_amdgcn_s_setprio(1);
#pragma unroll
    for (int kk = 0; kk < 2; ++kk) {
      int cb = kk * 64 + l4 * 16;
#pragma unroll
      for (int mf = 0; mf < 4; ++mf) {
        int r = mf * 16 + l15;
        bf16x8 kf = *(const bf16x8*)(sK + r * 128 + (cb ^ ((r & 7) << 4)));
        s[mf] = __builtin_amdgcn_mfma_f32_16x16x32_bf16(kf, aq[kk], s[mf], 0, 0, 0);
      }
    }
    __builtin_amdgcn_s_setprio(0);
    // 16-value max via max3-shaped tree (clang fuses nested fmaxf to v_max3)
    float t0 = fmaxf(fmaxf(s[0][0], s[0][1]), s[0][2]);
    float t1 = fmaxf(fmaxf(s[0][3], s[1][0]), s[1][1]);
    float t2 = fmaxf(fmaxf(s[1][2], s[1][3]), s[2][0]);
    float t3 = fmaxf(fmaxf(s[2][1], s[2][2]), s[2][3]);
    float t4 = fmaxf(fmaxf(s[3][0], s[3][1]), s[3][2]);
    float pm = fmaxf(fmaxf(fmaxf(t0, t1), t2), fmaxf(fmaxf(t3, t4), s[3][3]));
    pm = fmaxf(pm, __shfl_xor(pm, 16));
    pm = fmaxf(pm, __shfl_xor(pm, 32));
    if (!__all(pm <= m + 11.5f)) {     // T13 defer-max (log2 domain)
      float mn = fmaxf(m, pm);
      float al = __builtin_exp2f(m - mn);
      m = mn; lsum *= al;
#pragma unroll
      for (int df = 0; df < 4; ++df)
#pragma unroll
        for (int r = 0; r < 4; ++r) ctx[df][r] *= al;
    }
    float lp = 0.f;
#pragma unroll
    for (int mf = 0; mf < 4; ++mf)
#pragma unroll
      for (int r = 0; r < 4; ++r) {
        float p = __builtin_exp2f(s[mf][r] - m);
        s[mf][r] = p;
        lp += p;
      }
    lsum += lp;
    unsigned int pk[4][2];
#pragma unroll
    for (int mf = 0; mf < 4; ++mf) {
      asm("v_cvt_pk_bf16_f32 %0, %1, %2" : "=v"(pk[mf][0]) : "v"(s[mf][0]), "v"(s[mf][1]));
      asm("v_cvt_pk_bf16_f32 %0, %1, %2" : "=v"(pk[mf][1]) : "v"(s[mf][2]), "v"(s[mf][3]));
    }
    // ctx^T += V^T P^T
#pragma unroll
    for (int kk = 0; kk < 2; ++kk) {
      unsigned int q00 = __shfl((int)pk[2 * kk][0], srcA);
      unsigned int q10 = __shfl((int)pk[2 * kk + 1][0], srcA);
      unsigned int q01 = __shfl((int)pk[2 * kk][1], srcA);
      unsigned int q11 = __shfl((int)pk[2 * kk + 1][1], srcA);
      unsigned int r00 = __shfl((int)pk[2 * kk][0], srcB);
      unsigned int r10 = __shfl((int)pk[2 * kk + 1][0], srcB);
      unsigned int r01 = __shfl((int)pk[2 * kk][1], srcB);
      unsigned int r11 = __shfl((int)pk[2 * kk + 1][1], srcB);
      uint4 uu;
      uu.x = hi ? q10 : q00;
      uu.y = hi ? q11 : q01;
      uu.z = hi ? r10 : r00;
      uu.w = hi ? r11 : r01;
      bf16x8 pfrag = *(bf16x8*)&uu;
      int cb = kk * 64 + l4 * 16;
      __builtin_amdgcn_s_setprio(1);
#pragma unroll
      for (int df = 0; df < 4; ++df) {
        int rv = df * 16 + l15;
        bf16x8 vf = *(const bf16x8*)(sV + rv * 128 + (cb ^ ((rv & 7) << 4)));
        ctx[df] = __builtin_amdgcn_mfma_f32_16x16x32_bf16(vf, pfrag, ctx[df], 0, 0, 0);
      }
      __builtin_amdgcn_s_setprio(0);
    }
    __builtin_amdgcn_s_barrier();
    d ^= 1;
  }
  lsum += __shfl_xor(lsum, 16);
  lsum += __shfl_xor(lsum, 32);

  // ---- phase 2: prefetch proj operands (K/V region now dead), then LDS combine ----
  GLD16((const char*)b_proj + (w << 10) + (lane << 4), lds + P_BIAS + (w << 10));
  stageB(0, 0); stageB(1, 1);

  if (wh == 1) {                         // deposit half1 state
    char* cbase = lds + P_CTX1 + (wq << 12);
#pragma unroll
    for (int df = 0; df < 4; ++df) {
      int byte = l15 * 256 + df * 64 + l4 * 16;
      *(f32x4*)(cbase + (byte ^ ((l15 & 7) << 4))) = ctx[df];
    }
    if (l4 == 0)
      *(float2*)(lds + P_ML1 + wq * 128 + l15 * 8) = make_float2(m, lsum);
  }
  asm volatile("s_waitcnt lgkmcnt(0)" ::: "memory");
  __builtin_amdgcn_sched_barrier(0);
  __builtin_amdgcn_s_barrier();
  if (wh == 0) {                         // merge halves -> sA bf16 [64][64] swizzled
    char* cbase = lds + P_CTX1 + (wq << 12);
    float2 ml1 = *(const float2*)(lds + P_ML1 + wq * 128 + l15 * 8);
    float M = fmaxf(m, ml1.x);
    float a0 = __builtin_exp2f(m - M), a1 = __builtin_exp2f(ml1.x - M);
    float inv = 1.0f / (lsum * a0 + ml1.y * a1);
    a0 *= inv; a1 *= inv;
    int rq = wq * 16 + l15;
#pragma unroll
    for (int df = 0; df < 4; ++df) {
      int byte = l15 * 256 + df * 64 + l4 * 16;
      f32x4 c1 = *(const f32x4*)(cbase + (byte ^ ((l15 & 7) << 4)));
      u16x4 h;
      h[0] = f2bf(ctx[df][0] * a0 + c1[0] * a1);
      h[1] = f2bf(ctx[df][1] * a0 + c1[1] * a1);
      h[2] = f2bf(ctx[df][2] * a0 + c1[2] * a1);
      h[3] = f2bf(ctx[df][3] * a0 + c1[3] * a1);
      int sbyte = rq * 128 + ((df * 32 + l4 * 8) ^ ((rq & 7) << 4));
      *(u16x4*)(lds + P_SA + sbyte) = h;
    }
  }
  asm volatile("s_waitcnt lgkmcnt(0)" ::: "memory");
  __builtin_amdgcn_sched_barrier(0);
  __builtin_amdgcn_s_barrier();

  // ---- phase 3: proj chunk loop, 16 chunks of 128 cols ----
  // FIFO (stageB = 2 loads; stores = 4/chunk):
  // entry: [bias1, stB0(2), stB1(2)] = 5 -> c=0 vmcnt(2) drains bias+stB0.
  // c=1: [stB1(2), stores0(4), stage2(2)] = 8 -> vmcnt(6).
  // steady c in [2,14]: [st(c-2)(4), stage(c)(2), st(c-1)(4), stage(c+1)(2)] = 12 -> vmcnt(6).
  // c=15: [st13(4), stage15(2), st14(4)] = 10 -> vmcnt(4).
#pragma unroll
  for (int c = 0; c < 16; ++c) {
    if (c == 0)       asm volatile("s_waitcnt vmcnt(2) lgkmcnt(0)" ::: "memory");
    else if (c == 15) asm volatile("s_waitcnt vmcnt(4) lgkmcnt(0)" ::: "memory");
    else              asm volatile("s_waitcnt vmcnt(6) lgkmcnt(0)" ::: "memory");
    __builtin_amdgcn_s_barrier();
    const char* bB = lds + P_WPT + (c & 1) * 16384;
    f32x4 acc[4] = {};
    __builtin_amdgcn_s_setprio(1);
#pragma unroll
    for (int kk = 0; kk < 2; ++kk) {
      int cb = kk * 64 + l4 * 16;
      bf16x8 af[4], bfr;
#pragma unroll
      for (int mm = 0; mm < 4; ++mm) {
        int r = mm * 16 + l15;
        af[mm] = *(const bf16x8*)(lds + P_SA + r * 128 + (cb ^ ((r & 7) << 4)));
      }
      {
        int r = w * 16 + l15;
        bfr = *(const bf16x8*)(bB + r * 128 + (cb ^ ((r & 7) << 4)));
      }
      // swapped: A=wpT-rows (out cols), B=ctx-rows (out rows)
#pragma unroll
      for (int mm = 0; mm < 4; ++mm)
        acc[mm] = __builtin_amdgcn_mfma_f32_16x16x32_bf16(bfr, af[mm], acc[mm], 0, 0, 0);
    }
    __builtin_amdgcn_s_setprio(0);
#pragma unroll
    for (int mm = 0; mm < 4; ++mm) {
      int grow = qbase + mm * 16 + l15;
      int gcol = c * 128 + w * 16 + l4 * 4;
      float4 bias = *(const float4*)(lds + P_BIAS + gcol * 4);  // lgkm, FIFO-safe
      float4 o;
      o.x = acc[mm][0] + bias.x; o.y = acc[mm][1] + bias.y;
      o.z = acc[mm][2] + bias.z; o.w = acc[mm][3] + bias.w;
      *(float4*)(out + ((size_t)bb * 2048 + grow) * 2048 + gcol) = o;
    }
    __builtin_amdgcn_s_barrier();        // all reads of buf (c&1) done
    if (c < 14) stageB(c + 2, c & 1);
  }
}

// ---------- launch ----------
extern "C" void kernel_launch(void* const* d_in, const int* in_sizes, int n_in,
                              void* d_out, int out_size, void* d_ws, size_t ws_size,
                              hipStream_t stream) {
  const float* x      = (const float*)d_in[0];
  const float* W_qkv  = (const float*)d_in[1];
  const float* b_qkv  = (const float*)d_in[2];
  const float* W_proj = (const float*)d_in[3];
  const float* b_proj = (const float*)d_in[4];
  float* out = (float*)d_out;

  unsigned short* ws   = (unsigned short*)d_ws;
  unsigned short* wqT  = ws;                                   // 192*2048
  unsigned short* wpT  = wqT + (size_t)192 * 2048;             // 2048*64
  unsigned short* qb   = wpT + (size_t)2048 * 64;              // 16384*64 (pre-scaled)
  unsigned short* kb   = qb  + (size_t)16384 * 64;
  unsigned short* vt   = kb  + (size_t)16384 * 64;             // [8][64][2048]

  k_trw<<<64, 256, 0, stream>>>(W_qkv, W_proj, wqT, wpT);
  k_qkv<<<256, 512, 0, stream>>>(x, wqT, b_qkv, qb, kb, vt);
  k_attnproj<<<256, 512, 0, stream>>>(qb, kb, vt, wpT, b_proj, out);
}

// Round 12
// 90.959 us; speedup vs baseline: 1.2698x; 1.0023x over previous
//
#include <hip/hip_runtime.h>

// ---------- types ----------
typedef __bf16 bf16x8 __attribute__((ext_vector_type(8)));
typedef unsigned short u16x8 __attribute__((ext_vector_type(8)));
typedef unsigned short u16x4 __attribute__((ext_vector_type(4)));
typedef float  f32x4  __attribute__((ext_vector_type(4)));

#define QSCALE 0.1803368801111204f   // 0.125 * log2(e): S comes out in log2 domain

__device__ __forceinline__ unsigned short f2bf(float f) {
  unsigned int u = __float_as_uint(f);
  u = u + 0x7fffu + ((u >> 16) & 1u);   // RNE
  return (unsigned short)(u >> 16);
}

// global_load_lds, 16B per lane; LDS dest = wave-uniform base + lane*16
#define GLD16(src, dst)                                                        \
  __builtin_amdgcn_global_load_lds(                                            \
      (const __attribute__((address_space(1))) void*)(src),                    \
      (__attribute__((address_space(3))) void*)(dst), 16, 0, 0)

// All MFMA LDS tiles have 128-byte rows; swizzle: byte ^= (row&7)<<4 (both sides).

// ---------- 1. merged weight transposes (R11 verbatim) ----------
__global__ __launch_bounds__(256) void k_trw(const float* __restrict__ Wq,
                                             const float* __restrict__ Wp,
                                             unsigned short* __restrict__ wqT,
                                             unsigned short* __restrict__ wpT) {
  __shared__ float tile[64][193];
  const int t = threadIdx.x;
  if (blockIdx.x < 32) {
    const int k0 = blockIdx.x * 64;
#pragma unroll
    for (int i = 0; i < 12; ++i) {       // 64 rows x 48 float4
      int u = i * 256 + t;
      int row = u / 48, c4 = u % 48;
      float4 v = *(const float4*)(Wq + (size_t)(k0 + row) * 192 + c4 * 4);
      tile[row][c4 * 4 + 0] = v.x; tile[row][c4 * 4 + 1] = v.y;
      tile[row][c4 * 4 + 2] = v.z; tile[row][c4 * 4 + 3] = v.w;
    }
    __syncthreads();
#pragma unroll
    for (int i = 0; i < 6; ++i) {        // 192 cols x 8 u16x8
      int u = i * 256 + t;
      int c = u >> 3, k8 = (u & 7) * 8;
      u16x8 h;
#pragma unroll
      for (int j = 0; j < 8; ++j) h[j] = f2bf(tile[k8 + j][c]);
      *(u16x8*)(wqT + (size_t)c * 2048 + k0 + k8) = h;
    }
  } else {
    const int n0 = (blockIdx.x - 32) * 64;
#pragma unroll
    for (int i = 0; i < 4; ++i) {        // 64 d-rows x 16 float4
      int u = i * 256 + t;
      int dd = u >> 4, c4 = u & 15;
      float4 v = *(const float4*)(Wp + (size_t)dd * 2048 + n0 + c4 * 4);
      tile[dd][c4 * 4 + 0] = v.x; tile[dd][c4 * 4 + 1] = v.y;
      tile[dd][c4 * 4 + 2] = v.z; tile[dd][c4 * 4 + 3] = v.w;
    }
    __syncthreads();
#pragma unroll
    for (int i = 0; i < 2; ++i) {        // 64 n-rows x 8 u16x8
      int u = i * 256 + t;
      int n = u >> 3, d8 = (u & 7) * 8;
      u16x8 h;
      h[0] = f2bf(tile[d8 + 0][n]); h[1] = f2bf(tile[d8 + 1][n]);
      h[2] = f2bf(tile[d8 + 2][n]); h[3] = f2bf(tile[d8 + 3][n]);
      h[4] = f2bf(tile[d8 + 4][n]); h[5] = f2bf(tile[d8 + 5][n]);
      h[6] = f2bf(tile[d8 + 6][n]); h[7] = f2bf(tile[d8 + 7][n]);
      *(u16x8*)(wpT + (size_t)(n0 + n) * 64 + d8) = h;
    }
  }
}

// ---------- 2. fused QKV GEMM: [16384,2048] x [2048,192] ----------
// BM=64, BN=192, BK=64. 512 threads = 8 waves (2M x 4N), grid 256.
// B-before-A issue order, PINNED with sched_barrier(0) (R9's race was the
// scheduler reordering issueA vs stageB, breaking positional vmcnt).
// FIFO: entering step n: [A(n)2, B(n)3, A(n+1)2]; writeA's implicit
// register-dep wait drains A(n); +B(n+1)3 +A(n+2)2 -> vmcnt(7) drains
// exactly B(n); A(n+1) stays in flight ~2 steps (covers HBM latency).
__global__ __launch_bounds__(512) void k_qkv(const float* __restrict__ x,
                                             const unsigned short* __restrict__ wqT,
                                             const float* __restrict__ b_qkv,
                                             unsigned short* __restrict__ qb,
                                             unsigned short* __restrict__ kb,
                                             unsigned short* __restrict__ vt) {
  __shared__ __align__(16) char lds[65536];  // sA[d]: d*8192 ; sB[d]: 16384+d*24576
  const int t = threadIdx.x;
  const int lane = t & 63, w = t >> 6;
  const int l15 = lane & 15, l4 = lane >> 4;
  const int wm = w >> 2, wn = w & 3;
  const int m0 = blockIdx.x * 64;

  const int arow = t >> 3;            // 0..63
  const int akc  = (t & 7) * 8;       // 0..56
  const float* xrow = x + (size_t)(m0 + arow) * 2048 + akc;
  const int aoff = arow * 128 + ((akc * 2) ^ ((arow & 7) << 4));

  f32x4 acc[2][3] = {};
  float4 xa0_0, xa1_0, xa0_1, xa1_1;   // 2-deep x prefetch, parity = kt&1

  auto issueA_0 = [&](int kt) {
    xa0_0 = *(const float4*)(xrow + kt * 64);
    xa1_0 = *(const float4*)(xrow + kt * 64 + 4);
  };
  auto issueA_1 = [&](int kt) {
    xa0_1 = *(const float4*)(xrow + kt * 64);
    xa1_1 = *(const float4*)(xrow + kt * 64 + 4);
  };
  auto writeA_0 = [&]() {
    u16x8 h;
    h[0] = f2bf(xa0_0.x); h[1] = f2bf(xa0_0.y); h[2] = f2bf(xa0_0.z); h[3] = f2bf(xa0_0.w);
    h[4] = f2bf(xa1_0.x); h[5] = f2bf(xa1_0.y); h[6] = f2bf(xa1_0.z); h[7] = f2bf(xa1_0.w);
    *(u16x8*)(lds + 0 * 8192 + aoff) = h;
  };
  auto writeA_1 = [&]() {
    u16x8 h;
    h[0] = f2bf(xa0_1.x); h[1] = f2bf(xa0_1.y); h[2] = f2bf(xa0_1.z); h[3] = f2bf(xa0_1.w);
    h[4] = f2bf(xa1_1.x); h[5] = f2bf(xa1_1.y); h[6] = f2bf(xa1_1.z); h[7] = f2bf(xa1_1.w);
    *(u16x8*)(lds + 1 * 8192 + aoff) = h;
  };
  auto stageB = [&](int kt, int d) {
    char* bbase = lds + 16384 + d * 24576;
#pragma unroll
    for (int p = 0; p < 3; ++p) {
      int L = p * 8192 + (w << 10) + (lane << 4);
      int row = L >> 7;
      int cb = (L & 127) ^ ((row & 7) << 4);
      GLD16((const char*)wqT + (size_t)row * 4096 + kt * 128 + cb,
            bbase + p * 8192 + (w << 10));
    }
  };
  auto compute = [&](int d) {
    const char* aB = lds + d * 8192;
    const char* bB = lds + 16384 + d * 24576;
    __builtin_amdgcn_s_setprio(1);
#pragma unroll
    for (int kk = 0; kk < 2; ++kk) {
      int cb = kk * 64 + l4 * 16;
      bf16x8 af[2], bfr[3];
#pragma unroll
      for (int m = 0; m < 2; ++m) {
        int r = wm * 32 + m * 16 + l15;
        af[m] = *(const bf16x8*)(aB + r * 128 + (cb ^ ((r & 7) << 4)));
      }
#pragma unroll
      for (int n = 0; n < 3; ++n) {
        int r = wn * 48 + n * 16 + l15;
        bfr[n] = *(const bf16x8*)(bB + r * 128 + (cb ^ ((r & 7) << 4)));
      }
#pragma unroll
      for (int m = 0; m < 2; ++m)
#pragma unroll
        for (int n = 0; n < 3; ++n)
          acc[m][n] = __builtin_amdgcn_mfma_f32_16x16x32_bf16(af[m], bfr[n], acc[m][n], 0, 0, 0);
    }
    __builtin_amdgcn_s_setprio(0);
  };

#define QKV_STEP(n, P, DOI, DOS, W)                                    \
  {                                                                    \
    writeA_##P();                                                      \
    __builtin_amdgcn_sched_barrier(0);                                 \
    if (DOS) stageB((n) + 1, (P) ^ 1);                                 \
    __builtin_amdgcn_sched_barrier(0);                                 \
    if (DOI) issueA_##P((n) + 2);                                      \
    asm volatile("s_waitcnt vmcnt(" W ") lgkmcnt(0)" ::: "memory");    \
    __builtin_amdgcn_s_barrier();                                      \
    compute(P);                                                        \
    __builtin_amdgcn_s_barrier();                                      \
  }

  stageB(0, 0);
  __builtin_amdgcn_sched_barrier(0);
  issueA_0(0); issueA_1(1);
  for (int kt = 0; kt < 30; kt += 2) {
    QKV_STEP(kt,     0, true, true, "7");
    QKV_STEP(kt + 1, 1, true, true, "7");
  }
  QKV_STEP(30, 0, false, true,  "5");
  QKV_STEP(31, 1, false, false, "0");
#undef QKV_STEP

  // epilogue: C/D layout col=lane&15, row=(lane>>4)*4+reg
#pragma unroll
  for (int m = 0; m < 2; ++m)
#pragma unroll
    for (int n = 0; n < 3; ++n) {
      int c = wn * 48 + n * 16 + l15;   // 0..191
      int j = c >> 6, cc = c & 63;
      float bias = b_qkv[c];
      int grow0 = m0 + wm * 32 + m * 16 + l4 * 4;
      if (j == 0) {
#pragma unroll
        for (int r = 0; r < 4; ++r)
          qb[(size_t)(grow0 + r) * 64 + cc] = f2bf((acc[m][n][r] + bias) * QSCALE);
      } else if (j == 1) {
#pragma unroll
        for (int r = 0; r < 4; ++r)
          kb[(size_t)(grow0 + r) * 64 + cc] = f2bf(acc[m][n][r] + bias);
      } else {            // v transposed: [b][64][2048]
        int bbv = grow0 >> 11, nn0 = grow0 & 2047;
        u16x4 h;
        h[0] = f2bf(acc[m][n][0] + bias); h[1] = f2bf(acc[m][n][1] + bias);
        h[2] = f2bf(acc[m][n][2] + bias); h[3] = f2bf(acc[m][n][3] + bias);
        *(u16x4*)(vt + ((size_t)bbv * 64 + cc) * 2048 + nn0) = h;
      }
    }
}

// ---------- 3. fused attention + proj (R11 verbatim) ----------
#define P_CTX1 0          // [0, 16K): half1 ctx exchange (reuses K/V region)
#define P_ML1  16384      // [16K, 16K+512)
#define P_SA   24576      // [24K, 32K)
#define P_BIAS 32768      // [32K, 40K)   (written only AFTER phase 1 -- safe)
#define P_WPT  40960      // [40K, 72K): wpT dbuf 2 x 16K
__global__ __launch_bounds__(512) void k_attnproj(const unsigned short* __restrict__ qb,
                                                  const unsigned short* __restrict__ kb,
                                                  const unsigned short* __restrict__ vt,
                                                  const unsigned short* __restrict__ wpT,
                                                  const float* __restrict__ b_proj,
                                                  float* __restrict__ out) {
  __shared__ __align__(16) char lds[73728];
  const int t = threadIdx.x;
  const int lane = t & 63, w = t >> 6;
  const int l15 = lane & 15, l4 = lane >> 4;
  const int wq = w & 3, wh = w >> 2;
  const int lin = blockIdx.x;
  const int bb = lin & 7;              // batch-per-XCD
  const int qbase = (lin >> 3) * 64;
  const int q0 = qbase + wq * 16;
  const int kt0 = wh * 16;
  const unsigned short* qrow = qb + ((size_t)bb * 2048 + q0 + l15) * 64;
  bf16x8 aq[2];
  aq[0] = *(const bf16x8*)(qrow + l4 * 8);       // B-frag: col=l15(q), k=(l>>4)*8+j
  aq[1] = *(const bf16x8*)(qrow + 32 + l4 * 8);
  f32x4 ctx[4] = {};                              // ctx^T: q=l15, d=df*16+l4*4+r
  float m = -1e30f, lsum = 0.f;
  const char* kBase = (const char*)kb + (size_t)bb * 2048 * 128;
  const char* vBase = (const char*)vt + (size_t)bb * 64 * 4096;
  const int srcA = ((l4 & 1) << 5) | l15;
  const int srcB = srcA + 16;
  const bool hi = (l4 >> 1) & 1;

  auto stage = [&](int kt, int d) {
#pragma unroll
    for (int p = 0; p < 2; ++p) {
      int L = p * 4096 + (wq << 10) + (lane << 4);
      int row = L >> 7;
      int cb = (L & 127) ^ ((row & 7) << 4);
      GLD16(kBase + (size_t)(kt * 64 + row) * 128 + cb,
            lds + wh * 32768 + d * 8192 + p * 4096 + (wq << 10));
      GLD16(vBase + (size_t)row * 4096 + kt * 128 + cb,
            lds + wh * 32768 + 16384 + d * 8192 + p * 4096 + (wq << 10));
    }
  };
  auto stageB = [&](int c, int dd) {      // wpT rows [c*128, +128) -> 16KB
    char* bbase = lds + P_WPT + dd * 16384;
#pragma unroll
    for (int p = 0; p < 2; ++p) {         // 2 x (512 threads x 16B)
      int L = p * 8192 + t * 16;
      int row = L >> 7;
      int cb = (L & 127) ^ ((row & 7) << 4);
      GLD16((const char*)wpT + (size_t)(c * 128 + row) * 128 + cb,
            bbase + p * 8192 + (w << 10));
    }
  };

  // ---- phase 1 ----
  stage(kt0, 0);
  int d = 0;
  for (int kt = 0; kt < 16; ++kt) {
    if (kt < 15) {
      stage(kt0 + kt + 1, d ^ 1);
      asm volatile("s_waitcnt vmcnt(4)" ::: "memory");   // drains tile kt, keeps prefetch
    } else {
      asm volatile("s_waitcnt vmcnt(0)" ::: "memory");
    }
    __builtin_amdgcn_s_barrier();
    const char* sK = lds + wh * 32768 + d * 8192;
    const char* sV = lds + wh * 32768 + 16384 + d * 8192;
    // S^T = K Q^T : s[mf] holds q=l15, kv = mf*16 + l4*4 + r  (log2 domain)
    f32x4 s[4] = {};
    __builtin_amdgcn_s_setprio(1);
#pragma unroll
    for (int kk = 0; kk < 2; ++kk) {
      int cb = kk * 64 + l4 * 16;
#pragma unroll
      for (int mf = 0; mf < 4; ++mf) {
        int r = mf * 16 + l15;
        bf16x8 kf = *(const bf16x8*)(sK + r * 128 + (cb ^ ((r & 7) << 4)));
        s[mf] = __builtin_amdgcn_mfma_f32_16x16x32_bf16(kf, aq[kk], s[mf], 0, 0, 0);
      }
    }
    __builtin_amdgcn_s_setprio(0);
    // 16-value max via max3-shaped tree (clang fuses nested fmaxf to v_max3)
    float t0 = fmaxf(fmaxf(s[0][0], s[0][1]), s[0][2]);
    float t1 = fmaxf(fmaxf(s[0][3], s[1][0]), s[1][1]);
    float t2 = fmaxf(fmaxf(s[1][2], s[1][3]), s[2][0]);
    float t3 = fmaxf(fmaxf(s[2][1], s[2][2]), s[2][3]);
    float t4 = fmaxf(fmaxf(s[3][0], s[3][1]), s[3][2]);
    float pm = fmaxf(fmaxf(fmaxf(t0, t1), t2), fmaxf(fmaxf(t3, t4), s[3][3]));
    pm = fmaxf(pm, __shfl_xor(pm, 16));
    pm = fmaxf(pm, __shfl_xor(pm, 32));
    if (!__all(pm <= m + 11.5f)) {     // T13 defer-max (log2 domain)
      float mn = fmaxf(m, pm);
      float al = __builtin_exp2f(m - mn);
      m = mn; lsum *= al;
#pragma unroll
      for (int df = 0; df < 4; ++df)
#pragma unroll
        for (int r = 0; r < 4; ++r) ctx[df][r] *= al;
    }
    float lp = 0.f;
#pragma unroll
    for (int mf = 0; mf < 4; ++mf)
#pragma unroll
      for (int r = 0; r < 4; ++r) {
        float p = __builtin_exp2f(s[mf][r] - m);
        s[mf][r] = p;
        lp += p;
      }
    lsum += lp;
    unsigned int pk[4][2];
#pragma unroll
    for (int mf = 0; mf < 4; ++mf) {
      asm("v_cvt_pk_bf16_f32 %0, %1, %2" : "=v"(pk[mf][0]) : "v"(s[mf][0]), "v"(s[mf][1]));
      asm("v_cvt_pk_bf16_f32 %0, %1, %2" : "=v"(pk[mf][1]) : "v"(s[mf][2]), "v"(s[mf][3]));
    }
    // ctx^T += V^T P^T
#pragma unroll
    for (int kk = 0; kk < 2; ++kk) {
      unsigned int q00 = __shfl((int)pk[2 * kk][0], srcA);
      unsigned int q10 = __shfl((int)pk[2 * kk + 1][0], srcA);
      unsigned int q01 = __shfl((int)pk[2 * kk][1], srcA);
      unsigned int q11 = __shfl((int)pk[2 * kk + 1][1], srcA);
      unsigned int r00 = __shfl((int)pk[2 * kk][0], srcB);
      unsigned int r10 = __shfl((int)pk[2 * kk + 1][0], srcB);
      unsigned int r01 = __shfl((int)pk[2 * kk][1], srcB);
      unsigned int r11 = __shfl((int)pk[2 * kk + 1][1], srcB);
      uint4 uu;
      uu.x = hi ? q10 : q00;
      uu.y = hi ? q11 : q01;
      uu.z = hi ? r10 : r00;
      uu.w = hi ? r11 : r01;
      bf16x8 pfrag = *(bf16x8*)&uu;
      int cb = kk * 64 + l4 * 16;
      __builtin_amdgcn_s_setprio(1);
#pragma unroll
      for (int df = 0; df < 4; ++df) {
        int rv = df * 16 + l15;
        bf16x8 vf = *(const bf16x8*)(sV + rv * 128 + (cb ^ ((rv & 7) << 4)));
        ctx[df] = __builtin_amdgcn_mfma_f32_16x16x32_bf16(vf, pfrag, ctx[df], 0, 0, 0);
      }
      __builtin_amdgcn_s_setprio(0);
    }
    __builtin_amdgcn_s_barrier();
    d ^= 1;
  }
  lsum += __shfl_xor(lsum, 16);
  lsum += __shfl_xor(lsum, 32);

  // ---- phase 2: prefetch proj operands (K/V region now dead), then LDS combine ----
  GLD16((const char*)b_proj + (w << 10) + (lane << 4), lds + P_BIAS + (w << 10));
  stageB(0, 0); stageB(1, 1);

  if (wh == 1) {                         // deposit half1 state
    char* cbase = lds + P_CTX1 + (wq << 12);
#pragma unroll
    for (int df = 0; df < 4; ++df) {
      int byte = l15 * 256 + df * 64 + l4 * 16;
      *(f32x4*)(cbase + (byte ^ ((l15 & 7) << 4))) = ctx[df];
    }
    if (l4 == 0)
      *(float2*)(lds + P_ML1 + wq * 128 + l15 * 8) = make_float2(m, lsum);
  }
  asm volatile("s_waitcnt lgkmcnt(0)" ::: "memory");
  __builtin_amdgcn_sched_barrier(0);
  __builtin_amdgcn_s_barrier();
  if (wh == 0) {                         // merge halves -> sA bf16 [64][64] swizzled
    char* cbase = lds + P_CTX1 + (wq << 12);
    float2 ml1 = *(const float2*)(lds + P_ML1 + wq * 128 + l15 * 8);
    float M = fmaxf(m, ml1.x);
    float a0 = __builtin_exp2f(m - M), a1 = __builtin_exp2f(ml1.x - M);
    float inv = 1.0f / (lsum * a0 + ml1.y * a1);
    a0 *= inv; a1 *= inv;
    int rq = wq * 16 + l15;
#pragma unroll
    for (int df = 0; df < 4; ++df) {
      int byte = l15 * 256 + df * 64 + l4 * 16;
      f32x4 c1 = *(const f32x4*)(cbase + (byte ^ ((l15 & 7) << 4)));
      u16x4 h;
      h[0] = f2bf(ctx[df][0] * a0 + c1[0] * a1);
      h[1] = f2bf(ctx[df][1] * a0 + c1[1] * a1);
      h[2] = f2bf(ctx[df][2] * a0 + c1[2] * a1);
      h[3] = f2bf(ctx[df][3] * a0 + c1[3] * a1);
      int sbyte = rq * 128 + ((df * 32 + l4 * 8) ^ ((rq & 7) << 4));
      *(u16x4*)(lds + P_SA + sbyte) = h;
    }
  }
  asm volatile("s_waitcnt lgkmcnt(0)" ::: "memory");
  __builtin_amdgcn_sched_barrier(0);
  __builtin_amdgcn_s_barrier();

  // ---- phase 3: proj chunk loop, 16 chunks of 128 cols ----
  // FIFO (stageB = 2 loads; stores = 4/chunk):
  // entry: [bias1, stB0(2), stB1(2)] = 5 -> c=0 vmcnt(2) drains bias+stB0.
  // c=1: [stB1(2), stores0(4), stage2(2)] = 8 -> vmcnt(6).
  // steady c in [2,14]: [st(c-2)(4), stage(c)(2), st(c-1)(4), stage(c+1)(2)] = 12 -> vmcnt(6).
  // c=15: [st13(4), stage15(2), st14(4)] = 10 -> vmcnt(4).
#pragma unroll
  for (int c = 0; c < 16; ++c) {
    if (c == 0)       asm volatile("s_waitcnt vmcnt(2) lgkmcnt(0)" ::: "memory");
    else if (c == 15) asm volatile("s_waitcnt vmcnt(4) lgkmcnt(0)" ::: "memory");
    else              asm volatile("s_waitcnt vmcnt(6) lgkmcnt(0)" ::: "memory");
    __builtin_amdgcn_s_barrier();
    const char* bB = lds + P_WPT + (c & 1) * 16384;
    f32x4 acc[4] = {};
    __builtin_amdgcn_s_setprio(1);
#pragma unroll
    for (int kk = 0; kk < 2; ++kk) {
      int cb = kk * 64 + l4 * 16;
      bf16x8 af[4], bfr;
#pragma unroll
      for (int mm = 0; mm < 4; ++mm) {
        int r = mm * 16 + l15;
        af[mm] = *(const bf16x8*)(lds + P_SA + r * 128 + (cb ^ ((r & 7) << 4)));
      }
      {
        int r = w * 16 + l15;
        bfr = *(const bf16x8*)(bB + r * 128 + (cb ^ ((r & 7) << 4)));
      }
      // swapped: A=wpT-rows (out cols), B=ctx-rows (out rows)
#pragma unroll
      for (int mm = 0; mm < 4; ++mm)
        acc[mm] = __builtin_amdgcn_mfma_f32_16x16x32_bf16(bfr, af[mm], acc[mm], 0, 0, 0);
    }
    __builtin_amdgcn_s_setprio(0);
#pragma unroll
    for (int mm = 0; mm < 4; ++mm) {
      int grow = qbase + mm * 16 + l15;
      int gcol = c * 128 + w * 16 + l4 * 4;
      float4 bias = *(const float4*)(lds + P_BIAS + gcol * 4);  // lgkm, FIFO-safe
      float4 o;
      o.x = acc[mm][0] + bias.x; o.y = acc[mm][1] + bias.y;
      o.z = acc[mm][2] + bias.z; o.w = acc[mm][3] + bias.w;
      *(float4*)(out + ((size_t)bb * 2048 + grow) * 2048 + gcol) = o;
    }
    __builtin_amdgcn_s_barrier();        // all reads of buf (c&1) done
    if (c < 14) stageB(c + 2, c & 1);
  }
}

// ---------- launch ----------
extern "C" void kernel_launch(void* const* d_in, const int* in_sizes, int n_in,
                              void* d_out, int out_size, void* d_ws, size_t ws_size,
                              hipStream_t stream) {
  const float* x      = (const float*)d_in[0];
  const float* W_qkv  = (const float*)d_in[1];
  const float* b_qkv  = (const float*)d_in[2];
  const float* W_proj = (const float*)d_in[3];
  const float* b_proj = (const float*)d_in[4];
  float* out = (float*)d_out;

  unsigned short* ws   = (unsigned short*)d_ws;
  unsigned short* wqT  = ws;                                   // 192*2048
  unsigned short* wpT  = wqT + (size_t)192 * 2048;             // 2048*64
  unsigned short* qb   = wpT + (size_t)2048 * 64;              // 16384*64 (pre-scaled)
  unsigned short* kb   = qb  + (size_t)16384 * 64;
  unsigned short* vt   = kb  + (size_t)16384 * 64;             // [8][64][2048]

  k_trw<<<64, 256, 0, stream>>>(W_qkv, W_proj, wqT, wpT);
  k_qkv<<<256, 512, 0, stream>>>(x, wqT, b_qkv, qb, kb, vt);
  k_attnproj<<<256, 512, 0, stream>>>(qb, kb, vt, wpT, b_proj, out);
}